// Round 10
// baseline (744.494 us; speedup 1.0000x reference)
//
#include <hip/hip_runtime.h>

// ESIM layer: out = softmax((x@W + b) @ y^T) @ y
// B=64, Sx=Sy=512, D=1024, fp32 in/out.
//
// Round-11: attn phase-0 rebuilt as flash-style 2-pass over sy to break the
// register wall: acc s2[4][4]=64 regs (was 128) frees room for named BF0/BF1
// depth-2 B-prefetch (the stall fix that spilled in R3/R5/R8 for lack of
// registers). Pass 1: cols [w*64,+64) of sy[0,256), P1=exp(S-m1) unnormalized
// to Pbuf; pass 2: sy[256,512) with m=max(m1,m2) direct; P1 rescaled by
// exp(m1-m) in an LDS sweep; 1/sum folded into phase-2 output store.
// setprio removed (R9: null). proj/prep unchanged (R6 proven).

typedef float  f32x4  __attribute__((ext_vector_type(4)));
typedef _Float16 f16x8 __attribute__((ext_vector_type(8)));
typedef _Float16 f16x4 __attribute__((ext_vector_type(4)));
typedef __bf16 bf16x8 __attribute__((ext_vector_type(8)));
typedef __bf16 bf16x4 __attribute__((ext_vector_type(4)));

#define MFMA_F16(a, b, c)  __builtin_amdgcn_mfma_f32_16x16x32_f16((a), (b), (c), 0, 0, 0)
#define MFMA_BF16(a, b, c) __builtin_amdgcn_mfma_f32_16x16x32_bf16((a), (b), (c), 0, 0, 0)

#define WAIT_VM(N)  do { asm volatile("s_waitcnt vmcnt(" #N ")" ::: "memory"); \
                         __builtin_amdgcn_sched_barrier(0); } while (0)

__device__ __forceinline__ void async16(const void* g, void* lds) {
    __builtin_amdgcn_global_load_lds(
        (const __attribute__((address_space(1))) unsigned int*)g,
        (__attribute__((address_space(3))) unsigned int*)lds, 16, 0, 0);
}

// ========================= merged prep kernel ===============================
template <bool DOW>
__global__ void prep_all_kernel(const float* __restrict__ y, _Float16* __restrict__ yf,
                                _Float16* __restrict__ yT, const float* __restrict__ x,
                                f16x4* __restrict__ xh, f16x4* __restrict__ xl,
                                const float* __restrict__ W, _Float16* __restrict__ WT)
{
    __shared__ _Float16 LT[64][72];
    const int tid = threadIdx.x;
    const int bid = blockIdx.x;

    if (bid < 8192) {
        const int b   = bid >> 7;
        const int rem = bid & 127;
        const int sy0 = (rem >> 4) * 64;
        const int d0  = (rem & 15) * 64;
        const int r0 = tid >> 4;
        const int c4 = (tid & 15) * 4;
        #pragma unroll
        for (int i = 0; i < 4; ++i) {
            const int r = r0 + i * 16;
            const float4 v = *(const float4*)&y[((size_t)b * 512 + sy0 + r) * 1024 + d0 + c4];
            const f16x4 hv = {(_Float16)v.x, (_Float16)v.y, (_Float16)v.z, (_Float16)v.w};
            *(f16x4*)&yf[((size_t)b * 512 + sy0 + r) * 1024 + d0 + c4] = hv;
            #pragma unroll
            for (int cc = 0; cc < 4; ++cc) {
                const int c = (cc + (tid & 3)) & 3;
                LT[c4 + c][r] = hv[c];
            }
        }
        __syncthreads();
        #pragma unroll
        for (int i = 0; i < 4; ++i) {
            const int dr = r0 + i * 16;
            const f16x4 v = *(const f16x4*)&LT[dr][(tid & 15) * 4];
            *(f16x4*)&yT[((size_t)b * 1024 + d0 + dr) * 512 + sy0 + (tid & 15) * 4] = v;
        }
    } else if (bid < 10240) {
        int i = (bid - 8192) * 256 + tid;
        const float4* in = (const float4*)x;
        for (; i < 8388608; i += 2048 * 256) {
            const float4 v = in[i];
            const _Float16 h0 = (_Float16)v.x, h1 = (_Float16)v.y,
                           h2 = (_Float16)v.z, h3 = (_Float16)v.w;
            xh[i] = (f16x4){h0, h1, h2, h3};
            xl[i] = (f16x4){(_Float16)(v.x - (float)h0), (_Float16)(v.y - (float)h1),
                            (_Float16)(v.z - (float)h2), (_Float16)(v.w - (float)h3)};
        }
    } else if constexpr (DOW) {
        const int rem = bid - 10240;
        const int k0 = (rem >> 4) * 64;
        const int n0 = (rem & 15) * 64;
        const int r0 = tid >> 4;
        const int c4 = (tid & 15) * 4;
        #pragma unroll
        for (int i = 0; i < 4; ++i) {
            const int r = r0 + i * 16;
            const float4 v = *(const float4*)&W[(size_t)(k0 + r) * 1024 + n0 + c4];
            const f16x4 hv = {(_Float16)v.x, (_Float16)v.y, (_Float16)v.z, (_Float16)v.w};
            #pragma unroll
            for (int cc = 0; cc < 4; ++cc) {
                const int c = (cc + (tid & 3)) & 3;
                LT[c4 + c][r] = hv[c];
            }
        }
        __syncthreads();
        #pragma unroll
        for (int i = 0; i < 4; ++i) {
            const int dr = r0 + i * 16;
            const f16x4 v = *(const f16x4*)&LT[dr][(tid & 15) * 4];
            *(f16x4*)&WT[(size_t)(n0 + dr) * 1024 + k0 + (tid & 15) * 4] = v;
        }
    }
}

// ===================== K1: proj = x@W + b (fp16 2-term) =====================
template <bool PRE>
__global__ __launch_bounds__(256, 2)
void proj_f16_kernel(const _Float16* __restrict__ xh, const _Float16* __restrict__ xl,
                     const _Float16* __restrict__ WT, const float* __restrict__ W,
                     const float* __restrict__ bias, char* __restrict__ outc)
{
    __shared__ __align__(16) char psm[73728];   // 3 bufs x (Xh 8K | Xl 8K | Wf 8K)

    const int tid = threadIdx.x, lane = tid & 63, wave = tid >> 6;
    const int swz = (blockIdx.x & 7) * 256 + (blockIdx.x >> 3);
    const int m0 = (swz >> 3) * 128, n0 = (swz & 7) * 128;
    const int wm = (wave >> 1) * 64, wn = (wave & 1) * 64;
    const int ar = lane & 15;
    const int qs  = ((lane >> 4) ^ ((lane >> 1) & 3)) * 8;
    const int gcS = ((lane & 3) ^ ((lane >> 3) & 3)) * 8;
    const int lrow = lane >> 2;
    const int wkb = tid & 7;
    const int wn4 = (tid >> 3) * 4;

    f32x4 acc[4][4];
    #pragma unroll
    for (int i = 0; i < 4; ++i)
        #pragma unroll
        for (int j = 0; j < 4; ++j)
            acc[i][j] = (f32x4){0.f, 0.f, 0.f, 0.f};

    auto STAGE = [&](int t, int bi) {
        const int k0 = t * 32;
        _Float16 (*Xh)[32] = (_Float16(*)[32])(psm + bi * 24576);
        _Float16 (*Xl)[32] = (_Float16(*)[32])(psm + bi * 24576 + 8192);
        _Float16 (*Wf)[32] = (_Float16(*)[32])(psm + bi * 24576 + 16384);
        #pragma unroll
        for (int tt = 0; tt < 2; ++tt) {
            const int r = wave * 32 + tt * 16 + lrow;
            async16(&xh[(size_t)(m0 + r) * 1024 + k0 + gcS], &Xh[wave * 32 + tt * 16][0]);
            async16(&xl[(size_t)(m0 + r) * 1024 + k0 + gcS], &Xl[wave * 32 + tt * 16][0]);
            if constexpr (PRE)
                async16(&WT[(size_t)(n0 + r) * 1024 + k0 + gcS], &Wf[wave * 32 + tt * 16][0]);
        }
        if constexpr (!PRE) {
            const size_t wb = (size_t)(k0 + wkb * 4) * 1024 + n0 + wn4;
            const float4 v0 = *(const float4*)&W[wb];
            const float4 v1 = *(const float4*)&W[wb + 1024];
            const float4 v2 = *(const float4*)&W[wb + 2048];
            const float4 v3 = *(const float4*)&W[wb + 3072];
            const float rv[4][4] = {{v0.x, v0.y, v0.z, v0.w},
                                    {v1.x, v1.y, v1.z, v1.w},
                                    {v2.x, v2.y, v2.z, v2.w},
                                    {v3.x, v3.y, v3.z, v3.w}};
            #pragma unroll
            for (int j = 0; j < 4; ++j) {
                const int R = wn4 + j;
                const f16x4 hv = {(_Float16)rv[0][j], (_Float16)rv[1][j],
                                  (_Float16)rv[2][j], (_Float16)rv[3][j]};
                const int c = (wkb >> 1) ^ ((R >> 1) & 3);
                *(f16x4*)&Wf[R][c * 8 + (wkb & 1) * 4] = hv;
            }
        }
    };

    STAGE(0, 0);
    STAGE(1, 1);
    STAGE(2, 2);

    int bi = 0;
    for (int t = 0; t < 32; ++t) {
        if (t < 30)       { if constexpr (PRE) WAIT_VM(12); else WAIT_VM(8); }
        else if (t == 30) { if constexpr (PRE) WAIT_VM(6);  else WAIT_VM(4); }
        else              { WAIT_VM(0); }
        __builtin_amdgcn_s_barrier();

        _Float16 (*Xh)[32] = (_Float16(*)[32])(psm + bi * 24576);
        _Float16 (*Xl)[32] = (_Float16(*)[32])(psm + bi * 24576 + 8192);
        _Float16 (*Wf)[32] = (_Float16(*)[32])(psm + bi * 24576 + 16384);
        f16x8 ah[4], al[4], bfv[4];
        #pragma unroll
        for (int f = 0; f < 4; ++f) {
            ah[f]  = *(const f16x8*)&Xh[wm + f * 16 + ar][qs];
            al[f]  = *(const f16x8*)&Xl[wm + f * 16 + ar][qs];
            bfv[f] = *(const f16x8*)&Wf[wn + f * 16 + ar][qs];
        }
        #pragma unroll
        for (int i = 0; i < 4; ++i)
            #pragma unroll
            for (int j = 0; j < 4; ++j) {
                acc[i][j] = MFMA_F16(ah[i], bfv[j], acc[i][j]);
                acc[i][j] = MFMA_F16(al[i], bfv[j], acc[i][j]);
            }
        __builtin_amdgcn_s_barrier();

        if (t < 29) {
            STAGE(t + 3, bi);
            if constexpr (!PRE)
                asm volatile("s_waitcnt lgkmcnt(0)" ::: "memory");
        }
        bi = (bi == 2) ? 0 : bi + 1;
    }

    // epilogue: acc -> LDS (h/l interleaved row segments) -> coalesced stores
    _Float16* Ep = (_Float16*)psm;
    const int q4 = (lane >> 4) * 4;
    #pragma unroll
    for (int j = 0; j < 4; ++j) {
        const int nloc = wn + j * 16 + ar;
        const float bv = bias[n0 + nloc];
        const int nidx = (nloc >> 3) * 16 + (nloc & 7);
        #pragma unroll
        for (int i = 0; i < 4; ++i)
            #pragma unroll
            for (int r = 0; r < 4; ++r) {
                const int Rl = wm + i * 16 + q4 + r;
                const float v = acc[i][j][r] + bv;
                const _Float16 h = (_Float16)v;
                Ep[Rl * 256 + nidx]     = h;
                Ep[Rl * 256 + nidx + 8] = (_Float16)(v - (float)h);
            }
    }
    __syncthreads();
    #pragma unroll
    for (int c = 0; c < 16; ++c) {
        const int lin = c * 4096 + tid * 16;
        const int row = lin >> 9;
        const int off = lin & 511;
        *(float4*)(outc + (size_t)(m0 + row) * 4096 + n0 * 4 + off)
            = *(const float4*)(psm + lin);
    }
}

// ================= K2: attention per (batch, 64 sx rows), fp16 ==============
// Flash-style 2-pass phase 0: wave w -> sy cols [p*256 + w*64, +64) per pass;
// acc s2[4][4]=64 regs; BF0/BF1 depth-2 B-prefetch; A depth-2 as before.
// P stored unnormalized; pass-1 half rescaled by exp(m1-m); 1/sum folded into
// the phase-2 output store.
__global__ __launch_bounds__(256, 2)
void attn_f16_kernel(const _Float16* __restrict__ yf, const _Float16* __restrict__ yT,
                     char* __restrict__ outc)
{
    __shared__ _Float16 Pbuf[64][520];
    __shared__ float    Red[1024];
    // Red: [0..255] per-pass wave maxes | [256..511] sum1 | [512..575] m1 |
    //      [576..831] sum2

    const int tid = threadIdx.x, lane = tid & 63, wave = tid >> 6;
    const int swzb = (blockIdx.x & 7) * 64 + (blockIdx.x >> 3);
    const int b = swzb >> 3, sx0 = (swzb & 7) * 64;
    const int pbase = b * 512 + sx0;
    const int ar = lane & 15, q = lane >> 4, qk = q * 8;
    const size_t ybase = (size_t)b * 512 * 1024;

    const char* aptr = outc + (size_t)(pbase + ar) * 4096;   // + ri*65536

    f16x8 A0H[4], A0L[4], A1H[4], A1L[4];
    auto LOADA = [&](int kk, f16x8 (&AH)[4], f16x8 (&AL)[4]) {
        #pragma unroll
        for (int ri = 0; ri < 4; ++ri) {
            const char* p = aptr + (size_t)ri * 65536 + (size_t)(kk * 4 + q) * 32;
            AH[ri] = *(const f16x8*)p;
            AL[ri] = *(const f16x8*)(p + 16);
        }
    };
    f16x8 B0[4], B1[4];
    auto LOADB = [&](int cb, int kk, f16x8 (&Bv)[4]) {
        #pragma unroll
        for (int t = 0; t < 4; ++t)
            Bv[t] = *(const f16x8*)&yf[ybase + (size_t)(cb + t * 16 + ar) * 1024
                                       + kk * 32 + qk];
    };

    f32x4 s2[4][4];
    float mp1[4][4];   // pass-1 global max, live through pass 2
    float inv_[4][4];

    // ============================ PASS 1 (sy 0..255) ========================
    {
        const int cb = wave * 64;
        #pragma unroll
        for (int ri = 0; ri < 4; ++ri)
            #pragma unroll
            for (int t = 0; t < 4; ++t)
                s2[ri][t] = (f32x4){0.f, 0.f, 0.f, 0.f};
        LOADA(0, A0H, A0L);
        LOADA(1, A1H, A1L);
        LOADB(cb, 0, B0);
        LOADB(cb, 1, B1);
        for (int kk = 0; kk < 32; kk += 2) {
            #pragma unroll
            for (int ri = 0; ri < 4; ++ri)
                #pragma unroll
                for (int t = 0; t < 4; ++t) {
                    s2[ri][t] = MFMA_F16(A0H[ri], B0[t], s2[ri][t]);
                    s2[ri][t] = MFMA_F16(A0L[ri], B0[t], s2[ri][t]);
                }
            if (kk + 2 < 32) { LOADA(kk + 2, A0H, A0L); LOADB(cb, kk + 2, B0); }
            #pragma unroll
            for (int ri = 0; ri < 4; ++ri)
                #pragma unroll
                for (int t = 0; t < 4; ++t) {
                    s2[ri][t] = MFMA_F16(A1H[ri], B1[t], s2[ri][t]);
                    s2[ri][t] = MFMA_F16(A1L[ri], B1[t], s2[ri][t]);
                }
            if (kk + 3 < 32) { LOADA(kk + 3, A1H, A1L); LOADB(cb, kk + 3, B1); }
        }
        // wave-partial max over own 64 cols
        float pm[4][4];
        #pragma unroll
        for (int ri = 0; ri < 4; ++ri)
            #pragma unroll
            for (int r = 0; r < 4; ++r) {
                float m = -3.0e38f;
                #pragma unroll
                for (int t = 0; t < 4; ++t) m = fmaxf(m, s2[ri][t][r]);
                pm[ri][r] = m;
            }
        #pragma unroll
        for (int off = 1; off < 16; off <<= 1)
            #pragma unroll
            for (int ri = 0; ri < 4; ++ri)
                #pragma unroll
                for (int r = 0; r < 4; ++r)
                    pm[ri][r] = fmaxf(pm[ri][r], __shfl_xor(pm[ri][r], off, 64));
        if (ar == 0) {
            #pragma unroll
            for (int ri = 0; ri < 4; ++ri)
                #pragma unroll
                for (int r = 0; r < 4; ++r)
                    Red[wave * 64 + ri * 16 + q * 4 + r] = pm[ri][r];
        }
        __syncthreads();   // (A) pass-1 maxes visible
        #pragma unroll
        for (int ri = 0; ri < 4; ++ri)
            #pragma unroll
            for (int r = 0; r < 4; ++r) {
                const int row = ri * 16 + q * 4 + r;
                mp1[ri][r] = fmaxf(fmaxf(Red[row], Red[64 + row]),
                                   fmaxf(Red[128 + row], Red[192 + row]));
            }
        if (wave == 0 && ar == 0) {
            #pragma unroll
            for (int ri = 0; ri < 4; ++ri)
                #pragma unroll
                for (int r = 0; r < 4; ++r)
                    Red[512 + ri * 16 + q * 4 + r] = mp1[ri][r];
        }
        // P1 = exp(S - m1) (unnormalized), partial sums
        float ps[4][4];
        #pragma unroll
        for (int ri = 0; ri < 4; ++ri)
            #pragma unroll
            for (int r = 0; r < 4; ++r) {
                float sum = 0.f;
                #pragma unroll
                for (int t = 0; t < 4; ++t) {
                    const float e = __expf(s2[ri][t][r] - mp1[ri][r]);
                    s2[ri][t][r] = e;
                    sum += e;
                }
                ps[ri][r] = sum;
            }
        #pragma unroll
        for (int off = 1; off < 16; off <<= 1)
            #pragma unroll
            for (int ri = 0; ri < 4; ++ri)
                #pragma unroll
                for (int r = 0; r < 4; ++r)
                    ps[ri][r] += __shfl_xor(ps[ri][r], off, 64);
        if (ar == 0) {
            #pragma unroll
            for (int ri = 0; ri < 4; ++ri)
                #pragma unroll
                for (int r = 0; r < 4; ++r)
                    Red[256 + wave * 64 + ri * 16 + q * 4 + r] = ps[ri][r];
        }
        #pragma unroll
        for (int ri = 0; ri < 4; ++ri)
            #pragma unroll
            for (int t = 0; t < 4; ++t)
                #pragma unroll
                for (int r = 0; r < 4; ++r)
                    Pbuf[ri * 16 + q * 4 + r][cb + t * 16 + ar]
                        = (_Float16)s2[ri][t][r];
        __syncthreads();   // (B) sum1/m1 visible; Red[0..255] free for pass 2
    }

    // ============================ PASS 2 (sy 256..511) ======================
    {
        const int cb = 256 + wave * 64;
        #pragma unroll
        for (int ri = 0; ri < 4; ++ri)
            #pragma unroll
            for (int t = 0; t < 4; ++t)
                s2[ri][t] = (f32x4){0.f, 0.f, 0.f, 0.f};
        LOADA(0, A0H, A0L);
        LOADA(1, A1H, A1L);
        LOADB(cb, 0, B0);
        LOADB(cb, 1, B1);
        for (int kk = 0; kk < 32; kk += 2) {
            #pragma unroll
            for (int ri = 0; ri < 4; ++ri)
                #pragma unroll
                for (int t = 0; t < 4; ++t) {
                    s2[ri][t] = MFMA_F16(A0H[ri], B0[t], s2[ri][t]);
                    s2[ri][t] = MFMA_F16(A0L[ri], B0[t], s2[ri][t]);
                }
            if (kk + 2 < 32) { LOADA(kk + 2, A0H, A0L); LOADB(cb, kk + 2, B0); }
            #pragma unroll
            for (int ri = 0; ri < 4; ++ri)
                #pragma unroll
                for (int t = 0; t < 4; ++t) {
                    s2[ri][t] = MFMA_F16(A1H[ri], B1[t], s2[ri][t]);
                    s2[ri][t] = MFMA_F16(A1L[ri], B1[t], s2[ri][t]);
                }
            if (kk + 3 < 32) { LOADA(kk + 3, A1H, A1L); LOADB(cb, kk + 3, B1); }
        }
        float pm[4][4];
        #pragma unroll
        for (int ri = 0; ri < 4; ++ri)
            #pragma unroll
            for (int r = 0; r < 4; ++r) {
                float m = -3.0e38f;
                #pragma unroll
                for (int t = 0; t < 4; ++t) m = fmaxf(m, s2[ri][t][r]);
                pm[ri][r] = m;
            }
        #pragma unroll
        for (int off = 1; off < 16; off <<= 1)
            #pragma unroll
            for (int ri = 0; ri < 4; ++ri)
                #pragma unroll
                for (int r = 0; r < 4; ++r)
                    pm[ri][r] = fmaxf(pm[ri][r], __shfl_xor(pm[ri][r], off, 64));
        if (ar == 0) {
            #pragma unroll
            for (int ri = 0; ri < 4; ++ri)
                #pragma unroll
                for (int r = 0; r < 4; ++r)
                    Red[wave * 64 + ri * 16 + q * 4 + r] = pm[ri][r];
        }
        __syncthreads();   // (C) pass-2 maxes visible
        // m = max(m1, m2); P2 = exp(S - m) directly (no pass-2 rescale)
        float ps[4][4];
        #pragma unroll
        for (int ri = 0; ri < 4; ++ri)
            #pragma unroll
            for (int r = 0; r < 4; ++r) {
                const int row = ri * 16 + q * 4 + r;
                const float m2 = fmaxf(fmaxf(Red[row], Red[64 + row]),
                                       fmaxf(Red[128 + row], Red[192 + row]));
                const float m = fmaxf(mp1[ri][r], m2);
                float sum = 0.f;
                #pragma unroll
                for (int t = 0; t < 4; ++t) {
                    const float e = __expf(s2[ri][t][r] - m);
                    s2[ri][t][r] = e;
                    sum += e;
                }
                ps[ri][r] = sum;
            }
        #pragma unroll
        for (int off = 1; off < 16; off <<= 1)
            #pragma unroll
            for (int ri = 0; ri < 4; ++ri)
                #pragma unroll
                for (int r = 0; r < 4; ++r)
                    ps[ri][r] += __shfl_xor(ps[ri][r], off, 64);
        if (ar == 0) {
            #pragma unroll
            for (int ri = 0; ri < 4; ++ri)
                #pragma unroll
                for (int r = 0; r < 4; ++r)
                    Red[576 + wave * 64 + ri * 16 + q * 4 + r] = ps[ri][r];
        }
        #pragma unroll
        for (int ri = 0; ri < 4; ++ri)
            #pragma unroll
            for (int t = 0; t < 4; ++t)
                #pragma unroll
                for (int r = 0; r < 4; ++r)
                    Pbuf[ri * 16 + q * 4 + r][cb + t * 16 + ar]
                        = (_Float16)s2[ri][t][r];
        __syncthreads();   // (D) all P writes + sums visible
    }

    // ---- rescale pass-1 half by exp(m1-m); compute inv = 1/sum ----
    {
        const int srow = tid >> 2;
        const int c0 = (tid & 3) * 64;
        const float m1r = Red[512 + srow];
        const float m2r = fmaxf(fmaxf(Red[srow], Red[64 + srow]),
                                fmaxf(Red[128 + srow], Red[192 + srow]));
        const float a1 = __expf(m1r - fmaxf(m1r, m2r));
        #pragma unroll
        for (int cs = 0; cs < 8; ++cs) {
            f16x8 v = *(f16x8*)&Pbuf[srow][c0 + cs * 8];
            #pragma unroll
            for (int e = 0; e < 8; ++e)
                v[e] = (_Float16)((float)v[e] * a1);
            *(f16x8*)&Pbuf[srow][c0 + cs * 8] = v;
        }
    }
    #pragma unroll
    for (int ri = 0; ri < 4; ++ri)
        #pragma unroll
        for (int r = 0; r < 4; ++r) {
            const int row = ri * 16 + q * 4 + r;
            const float m1r = Red[512 + row];
            const float m2r = fmaxf(fmaxf(Red[row], Red[64 + row]),
                                    fmaxf(Red[128 + row], Red[192 + row]));
            const float a1 = __expf(m1r - fmaxf(m1r, m2r));
            const float s1 = Red[256 + row] + Red[320 + row] + Red[384 + row]
                           + Red[448 + row];
            const float s2v = Red[576 + row] + Red[640 + row] + Red[704 + row]
                            + Red[768 + row];
            inv_[ri][r] = 1.0f / (a1 * s1 + s2v);
        }
    __syncthreads();   // (E) rescale complete before phase-2 reads

    // ---- phase 2: O = P @ y via yT; wave w -> d cols [w*256, +256), 2 epochs
    float* outF = (float*)outc;
    #pragma unroll
    for (int dc = 0; dc < 2; ++dc) {
        f32x4 o2[4][8];
        #pragma unroll
        for (int ri = 0; ri < 4; ++ri)
            #pragma unroll
            for (int t = 0; t < 8; ++t)
                o2[ri][t] = (f32x4){0.f, 0.f, 0.f, 0.f};

        const _Float16* ytw = yT + ((size_t)b * 1024 + wave * 256 + dc * 128 + ar) * 512;

        for (int kk = 0; kk < 16; ++kk) {
            f16x8 a2[4], b2[8];
            #pragma unroll
            for (int ri = 0; ri < 4; ++ri)
                a2[ri] = *(const f16x8*)&Pbuf[ri * 16 + ar][kk * 32 + qk];
            #pragma unroll
            for (int t = 0; t < 8; ++t)
                b2[t] = *(const f16x8*)&ytw[(size_t)t * 16 * 512 + kk * 32 + qk];
            #pragma unroll
            for (int ri = 0; ri < 4; ++ri)
                #pragma unroll
                for (int t = 0; t < 8; ++t)
                    o2[ri][t] = MFMA_F16(a2[ri], b2[t], o2[ri][t]);
        }
        #pragma unroll
        for (int ri = 0; ri < 4; ++ri)
            #pragma unroll
            for (int t = 0; t < 8; ++t)
                #pragma unroll
                for (int r = 0; r < 4; ++r)
                    outF[(size_t)(pbase + ri * 16 + q * 4 + r) * 1024
                         + wave * 256 + dc * 128 + t * 16 + ar]
                        = o2[ri][t][r] * inv_[ri][r];
    }
}

// ===================== fallback path (round-1, known good) ==================

__device__ __forceinline__ void cvt4(const float4 v, bf16x4& h, bf16x4& l) {
    const float f0 = v.x, f1 = v.y, f2 = v.z, f3 = v.w;
    const __bf16 h0 = (__bf16)f0, h1 = (__bf16)f1, h2 = (__bf16)f2, h3 = (__bf16)f3;
    h = (bf16x4){h0, h1, h2, h3};
    l = (bf16x4){(__bf16)(f0 - (float)h0), (__bf16)(f1 - (float)h1),
                 (__bf16)(f2 - (float)h2), (__bf16)(f3 - (float)h3)};
}

__global__ __launch_bounds__(256, 2)
void proj_kernel_fb(const float* __restrict__ x, const float* __restrict__ W,
                    const float* __restrict__ bias, float* __restrict__ proj)
{
    __shared__ __bf16 Ah[128][40];
    __shared__ __bf16 Al[128][40];
    __shared__ __bf16 Bh[128][40];
    __shared__ __bf16 Bl[128][40];

    const int tid = threadIdx.x, lane = tid & 63, wave = tid >> 6;
    const int wm = (wave >> 1) * 64, wn = (wave & 1) * 64;
    const int m0 = (blockIdx.x >> 3) * 128, n0 = (blockIdx.x & 7) * 128;
    const int ar = lane & 15, ak = (lane >> 4) * 8;

    f32x4 acc[4][4];
    #pragma unroll
    for (int i = 0; i < 4; ++i)
        #pragma unroll
        for (int j = 0; j < 4; ++j)
            acc[i][j] = (f32x4){0.f, 0.f, 0.f, 0.f};

    const int xr = tid >> 3, xc = (tid & 7) * 4;
    const int wkb = tid >> 5, wn4 = (tid & 31) * 4;

    for (int k0 = 0; k0 < 1024; k0 += 32) {
        __syncthreads();
        #pragma unroll
        for (int it = 0; it < 4; ++it) {
            const int r = xr + it * 32;
            const float4 v = *(const float4*)&x[(size_t)(m0 + r) * 1024 + k0 + xc];
            bf16x4 h, l; cvt4(v, h, l);
            *(bf16x4*)&Ah[r][xc] = h;
            *(bf16x4*)&Al[r][xc] = l;
        }
        {
            const size_t wb = (size_t)(k0 + wkb * 4) * 1024 + n0 + wn4;
            const float4 v0 = *(const float4*)&W[wb];
            const float4 v1 = *(const float4*)&W[wb + 1024];
            const float4 v2 = *(const float4*)&W[wb + 2048];
            const float4 v3 = *(const float4*)&W[wb + 3072];
            const float rv[4][4] = {{v0.x, v0.y, v0.z, v0.w},
                                    {v1.x, v1.y, v1.z, v1.w},
                                    {v2.x, v2.y, v2.z, v2.w},
                                    {v3.x, v3.y, v3.z, v3.w}};
            #pragma unroll
            for (int j = 0; j < 4; ++j) {
                bf16x4 h, l;
                #pragma unroll
                for (int kk = 0; kk < 4; ++kk) {
                    const float f = rv[kk][j];
                    const __bf16 hb = (__bf16)f;
                    h[kk] = hb;
                    l[kk] = (__bf16)(f - (float)hb);
                }
                *(bf16x4*)&Bh[wn4 + j][wkb * 4] = h;
                *(bf16x4*)&Bl[wn4 + j][wkb * 4] = l;
            }
        }
        __syncthreads();

        bf16x8 a_h[4], a_l[4], b_h[4], b_l[4];
        #pragma unroll
        for (int f = 0; f < 4; ++f) {
            a_h[f] = *(const bf16x8*)&Ah[wm + f * 16 + ar][ak];
            a_l[f] = *(const bf16x8*)&Al[wm + f * 16 + ar][ak];
            b_h[f] = *(const bf16x8*)&Bh[wn + f * 16 + ar][ak];
            b_l[f] = *(const bf16x8*)&Bl[wn + f * 16 + ar][ak];
        }
        #pragma unroll
        for (int i = 0; i < 4; ++i)
            #pragma unroll
            for (int j = 0; j < 4; ++j) {
                acc[i][j] = MFMA_BF16(a_h[i], b_h[j], acc[i][j]);
                acc[i][j] = MFMA_BF16(a_l[i], b_h[j], acc[i][j]);
                acc[i][j] = MFMA_BF16(a_h[i], b_l[j], acc[i][j]);
            }
    }

    const int q4 = (lane >> 4) * 4;
    #pragma unroll
    for (int j = 0; j < 4; ++j) {
        const int n = n0 + wn + j * 16 + ar;
        const float bv = bias[n];
        #pragma unroll
        for (int i = 0; i < 4; ++i) {
            const size_t base = (size_t)(m0 + wm + i * 16 + q4) * 1024 + n;
            #pragma unroll
            for (int r = 0; r < 4; ++r)
                proj[base + (size_t)r * 1024] = acc[i][j][r] + bv;
        }
    }
}

__global__ __launch_bounds__(256, 1)
void attn_kernel_fb(const float* __restrict__ y, float* __restrict__ out)
{
    __shared__ __bf16 Ph[64][40];
    __shared__ __bf16 Pl[64][40];
    __shared__ __bf16 Yh[128][40];
    __shared__ __bf16 Yl[128][40];
    __shared__ __bf16 Pbuf[64][520];

    const int tid = threadIdx.x, lane = tid & 63, wave = tid >> 6;
    const int b = blockIdx.x >> 3, sx0 = (blockIdx.x & 7) * 64;
    const size_t ybase = (size_t)b * 512 * 1024;
    const size_t pbase = ((size_t)b * 512 + sx0) * 1024;
    const int ar = lane & 15, ak = (lane >> 4) * 8, q = lane >> 4;

    f32x4 s[4][8];
    #pragma unroll
    for (int nb = 0; nb < 4; ++nb)
        #pragma unroll
        for (int f = 0; f < 8; ++f)
            s[nb][f] = (f32x4){0.f, 0.f, 0.f, 0.f};

    const int pr = tid >> 3, pc = (tid & 7) * 4;

    for (int k0 = 0; k0 < 1024; k0 += 32) {
        __syncthreads();
        #pragma unroll
        for (int it = 0; it < 2; ++it) {
            const int r = pr + it * 32;
            const float4 v = *(const float4*)&out[pbase + (size_t)r * 1024 + k0 + pc];
            bf16x4 h, l; cvt4(v, h, l);
            *(bf16x4*)&Ph[r][pc] = h;
            *(bf16x4*)&Pl[r][pc] = l;
        }
        #pragma unroll
        for (int nb = 0; nb < 4; ++nb) {
            if (nb) __syncthreads();
            const int sy0 = nb * 128;
            #pragma unroll
            for (int it = 0; it < 4; ++it) {
                const int r = pr + it * 32;
                const float4 v = *(const float4*)&y[ybase + (size_t)(sy0 + r) * 1024 + k0 + pc];
                bf16x4 h, l; cvt4(v, h, l);
                *(bf16x4*)&Yh[r][pc] = h;
                *(bf16x4*)&Yl[r][pc] = l;
            }
            __syncthreads();
            const bf16x8 a_h = *(const bf16x8*)&Ph[wave * 16 + ar][ak];
            const bf16x8 a_l = *(const bf16x8*)&Pl[wave * 16 + ar][ak];
            #pragma unroll
            for (int f = 0; f < 8; ++f) {
                const bf16x8 b_h = *(const bf16x8*)&Yh[f * 16 + ar][ak];
                const bf16x8 b_l = *(const bf16x8*)&Yl[f * 16 + ar][ak];
                s[nb][f] = MFMA_BF16(a_h, b_h, s[nb][f]);
                s[nb][f] = MFMA_BF16(a_l, b_h, s[nb][f]);
                s[nb][f] = MFMA_BF16(a_h, b_l, s[nb][f]);
            }
        }
    }

    #pragma unroll
    for (int r = 0; r < 4; ++r) {
        float m = -3.0e38f;
        #pragma unroll
        for (int nb = 0; nb < 4; ++nb)
            #pragma unroll
            for (int f = 0; f < 8; ++f)
                m = fmaxf(m, s[nb][f][r]);
        #pragma unroll
        for (int off = 1; off < 16; off <<= 1)
            m = fmaxf(m, __shfl_xor(m, off, 64));
        float sum = 0.f;
        #pragma unroll
        for (int nb = 0; nb < 4; ++nb)
            #pragma unroll
            for (int f = 0; f < 8; ++f) {
                const float e = __expf(s[nb][f][r] - m);
                s[nb][f][r] = e;
                sum += e;
            }
        #pragma unroll
        for (int off = 1; off < 16; off <<= 1)
            sum += __shfl_xor(sum, off, 64);
        const float inv = 1.0f / sum;
        #pragma unroll
        for (int nb = 0; nb < 4; ++nb)
            #pragma unroll
            for (int f = 0; f < 8; ++f)
                s[nb][f][r] *= inv;
    }
    #pragma unroll
    for (int nb = 0; nb < 4; ++nb)
        #pragma unroll
        for (int f = 0; f < 8; ++f)
            #pragma unroll
            for (int r = 0; r < 4; ++r)
                Pbuf[wave * 16 + q * 4 + r][nb * 128 + f * 16 + ar] = (__bf16)s[nb][f][r];

    const int y2kb = tid >> 5, y2n4 = (tid & 31) * 4;
    for (int d0 = 0; d0 < 1024; d0 += 128) {
        f32x4 o[8];
        #pragma unroll
        for (int f = 0; f < 8; ++f) o[f] = (f32x4){0.f, 0.f, 0.f, 0.f};

        for (int k0 = 0; k0 < 512; k0 += 32) {
            __syncthreads();
            const size_t yb = ybase + (size_t)(k0 + y2kb * 4) * 1024 + d0 + y2n4;
            const float4 v0 = *(const float4*)&y[yb];
            const float4 v1 = *(const float4*)&y[yb + 1024];
            const float4 v2 = *(const float4*)&y[yb + 2048];
            const float4 v3 = *(const float4*)&y[yb + 3072];
            const float rv[4][4] = {{v0.x, v0.y, v0.z, v0.w},
                                    {v1.x, v1.y, v1.z, v1.w},
                                    {v2.x, v2.y, v2.z, v2.w},
                                    {v3.x, v3.y, v3.z, v3.w}};
            #pragma unroll
            for (int j = 0; j < 4; ++j) {
                const bf16x4 h = (bf16x4){(__bf16)rv[0][j], (__bf16)rv[1][j],
                                          (__bf16)rv[2][j], (__bf16)rv[3][j]};
                *(bf16x4*)&Yh[y2n4 + j][y2kb * 4] = h;
            }
            __syncthreads();
            const bf16x8 a = *(const bf16x8*)&Pbuf[wave * 16 + ar][k0 + ak];
            #pragma unroll
            for (int f = 0; f < 8; ++f) {
                const bf16x8 bb = *(const bf16x8*)&Yh[f * 16 + ar][ak];
                o[f] = MFMA_BF16(a, bb, o[f]);
            }
        }
        #pragma unroll
        for (int f = 0; f < 8; ++f)
            #pragma unroll
            for (int r = 0; r < 4; ++r)
                out[pbase + (size_t)(wave * 16 + q * 4 + r) * 1024 + d0 + f * 16 + ar] = o[f][r];
    }
}

// ============================== launch ======================================

extern "C" void kernel_launch(void* const* d_in, const int* in_sizes, int n_in,
                              void* d_out, int out_size, void* d_ws, size_t ws_size,
                              hipStream_t stream) {
    (void)in_sizes; (void)n_in; (void)out_size;
    const float* x    = (const float*)d_in[0];
    const float* y    = (const float*)d_in[1];
    const float* W    = (const float*)d_in[2];
    const float* bias = (const float*)d_in[3];

    if (ws_size >= 268435456ULL) {
        _Float16* yf = (_Float16*)d_ws;
        _Float16* yT = yf + 33554432;
        _Float16* xh = yT + 33554432;
        _Float16* xl = xh + 33554432;
        _Float16* WT = xl + 33554432;
        const bool pre = ws_size >= 268435456ULL + 2097152ULL;

        if (pre) {
            prep_all_kernel<true><<<dim3(10496), dim3(256), 0, stream>>>(
                y, yf, yT, x, (f16x4*)xh, (f16x4*)xl, W, WT);
            proj_f16_kernel<true><<<dim3(2048), dim3(256), 0, stream>>>(xh, xl, WT, W, bias,
                                                                        (char*)d_out);
        } else {
            prep_all_kernel<false><<<dim3(10240), dim3(256), 0, stream>>>(
                y, yf, yT, x, (f16x4*)xh, (f16x4*)xl, W, nullptr);
            proj_f16_kernel<false><<<dim3(2048), dim3(256), 0, stream>>>(xh, xl, nullptr, W,
                                                                         bias, (char*)d_out);
        }
        attn_f16_kernel<<<dim3(512), dim3(256), 0, stream>>>(yf, yT, (char*)d_out);
    } else {
        float* out = (float*)d_out;
        proj_kernel_fb<<<dim3(256 * 8), dim3(256), 0, stream>>>(x, W, bias, out);
        attn_kernel_fb<<<dim3(64 * 8), dim3(256), 0, stream>>>(y, out);
    }
}

// Round 11
// 689.024 us; speedup vs baseline: 1.0805x; 1.0805x over previous
//
#include <hip/hip_runtime.h>

// ESIM layer: out = softmax((x@W + b) @ y^T) @ y
// B=64, Sx=Sy=512, D=1024, fp32 in/out.
//
// Round-12: recombination of best-measured components (no new structure):
//  * attn: R2's kernel VERBATIM (211us, best attn ever measured; clean
//    counters) -- col-split, per-wave LDS stripe staged 1 iter ahead,
//    WAIT_VM(0)/LGKM(0) per kk -- with A-loads updated to the interleaved
//    h/l row-slot layout (h at (kk*4+q)*32, l at +16).
//  * proj: R6 counted-vmcnt triple-buffer (kept). prep: merged (kept).
// Ledger: 7 attn-restructure attempts (R3/R5/R7/R8/R10 + setprio R9) all
// regressed or null; R2 structure is the empirical optimum.

typedef float  f32x4  __attribute__((ext_vector_type(4)));
typedef _Float16 f16x8 __attribute__((ext_vector_type(8)));
typedef _Float16 f16x4 __attribute__((ext_vector_type(4)));
typedef __bf16 bf16x8 __attribute__((ext_vector_type(8)));
typedef __bf16 bf16x4 __attribute__((ext_vector_type(4)));

#define MFMA_F16(a, b, c)  __builtin_amdgcn_mfma_f32_16x16x32_f16((a), (b), (c), 0, 0, 0)
#define MFMA_BF16(a, b, c) __builtin_amdgcn_mfma_f32_16x16x32_bf16((a), (b), (c), 0, 0, 0)

#define WAIT_VM(N)  do { asm volatile("s_waitcnt vmcnt(" #N ")" ::: "memory"); \
                         __builtin_amdgcn_sched_barrier(0); } while (0)
#define WAIT_LGKM0() do { asm volatile("s_waitcnt lgkmcnt(0)" ::: "memory"); \
                          __builtin_amdgcn_sched_barrier(0); } while (0)

__device__ __forceinline__ void async16(const void* g, void* lds) {
    __builtin_amdgcn_global_load_lds(
        (const __attribute__((address_space(1))) unsigned int*)g,
        (__attribute__((address_space(3))) unsigned int*)lds, 16, 0, 0);
}

// ========================= merged prep kernel ===============================
template <bool DOW>
__global__ void prep_all_kernel(const float* __restrict__ y, _Float16* __restrict__ yf,
                                _Float16* __restrict__ yT, const float* __restrict__ x,
                                f16x4* __restrict__ xh, f16x4* __restrict__ xl,
                                const float* __restrict__ W, _Float16* __restrict__ WT)
{
    __shared__ _Float16 LT[64][72];
    const int tid = threadIdx.x;
    const int bid = blockIdx.x;

    if (bid < 8192) {
        const int b   = bid >> 7;
        const int rem = bid & 127;
        const int sy0 = (rem >> 4) * 64;
        const int d0  = (rem & 15) * 64;
        const int r0 = tid >> 4;
        const int c4 = (tid & 15) * 4;
        #pragma unroll
        for (int i = 0; i < 4; ++i) {
            const int r = r0 + i * 16;
            const float4 v = *(const float4*)&y[((size_t)b * 512 + sy0 + r) * 1024 + d0 + c4];
            const f16x4 hv = {(_Float16)v.x, (_Float16)v.y, (_Float16)v.z, (_Float16)v.w};
            *(f16x4*)&yf[((size_t)b * 512 + sy0 + r) * 1024 + d0 + c4] = hv;
            #pragma unroll
            for (int cc = 0; cc < 4; ++cc) {
                const int c = (cc + (tid & 3)) & 3;
                LT[c4 + c][r] = hv[c];
            }
        }
        __syncthreads();
        #pragma unroll
        for (int i = 0; i < 4; ++i) {
            const int dr = r0 + i * 16;
            const f16x4 v = *(const f16x4*)&LT[dr][(tid & 15) * 4];
            *(f16x4*)&yT[((size_t)b * 1024 + d0 + dr) * 512 + sy0 + (tid & 15) * 4] = v;
        }
    } else if (bid < 10240) {
        int i = (bid - 8192) * 256 + tid;
        const float4* in = (const float4*)x;
        for (; i < 8388608; i += 2048 * 256) {
            const float4 v = in[i];
            const _Float16 h0 = (_Float16)v.x, h1 = (_Float16)v.y,
                           h2 = (_Float16)v.z, h3 = (_Float16)v.w;
            xh[i] = (f16x4){h0, h1, h2, h3};
            xl[i] = (f16x4){(_Float16)(v.x - (float)h0), (_Float16)(v.y - (float)h1),
                            (_Float16)(v.z - (float)h2), (_Float16)(v.w - (float)h3)};
        }
    } else if constexpr (DOW) {
        const int rem = bid - 10240;
        const int k0 = (rem >> 4) * 64;
        const int n0 = (rem & 15) * 64;
        const int r0 = tid >> 4;
        const int c4 = (tid & 15) * 4;
        #pragma unroll
        for (int i = 0; i < 4; ++i) {
            const int r = r0 + i * 16;
            const float4 v = *(const float4*)&W[(size_t)(k0 + r) * 1024 + n0 + c4];
            const f16x4 hv = {(_Float16)v.x, (_Float16)v.y, (_Float16)v.z, (_Float16)v.w};
            #pragma unroll
            for (int cc = 0; cc < 4; ++cc) {
                const int c = (cc + (tid & 3)) & 3;
                LT[c4 + c][r] = hv[c];
            }
        }
        __syncthreads();
        #pragma unroll
        for (int i = 0; i < 4; ++i) {
            const int dr = r0 + i * 16;
            const f16x4 v = *(const f16x4*)&LT[dr][(tid & 15) * 4];
            *(f16x4*)&WT[(size_t)(n0 + dr) * 1024 + k0 + (tid & 15) * 4] = v;
        }
    }
}

// ===================== K1: proj = x@W + b (fp16 2-term) =====================
template <bool PRE>
__global__ __launch_bounds__(256, 2)
void proj_f16_kernel(const _Float16* __restrict__ xh, const _Float16* __restrict__ xl,
                     const _Float16* __restrict__ WT, const float* __restrict__ W,
                     const float* __restrict__ bias, char* __restrict__ outc)
{
    __shared__ __align__(16) char psm[73728];   // 3 bufs x (Xh 8K | Xl 8K | Wf 8K)

    const int tid = threadIdx.x, lane = tid & 63, wave = tid >> 6;
    const int swz = (blockIdx.x & 7) * 256 + (blockIdx.x >> 3);
    const int m0 = (swz >> 3) * 128, n0 = (swz & 7) * 128;
    const int wm = (wave >> 1) * 64, wn = (wave & 1) * 64;
    const int ar = lane & 15;
    const int qs  = ((lane >> 4) ^ ((lane >> 1) & 3)) * 8;
    const int gcS = ((lane & 3) ^ ((lane >> 3) & 3)) * 8;
    const int lrow = lane >> 2;
    const int wkb = tid & 7;
    const int wn4 = (tid >> 3) * 4;

    f32x4 acc[4][4];
    #pragma unroll
    for (int i = 0; i < 4; ++i)
        #pragma unroll
        for (int j = 0; j < 4; ++j)
            acc[i][j] = (f32x4){0.f, 0.f, 0.f, 0.f};

    auto STAGE = [&](int t, int bi) {
        const int k0 = t * 32;
        _Float16 (*Xh)[32] = (_Float16(*)[32])(psm + bi * 24576);
        _Float16 (*Xl)[32] = (_Float16(*)[32])(psm + bi * 24576 + 8192);
        _Float16 (*Wf)[32] = (_Float16(*)[32])(psm + bi * 24576 + 16384);
        #pragma unroll
        for (int tt = 0; tt < 2; ++tt) {
            const int r = wave * 32 + tt * 16 + lrow;
            async16(&xh[(size_t)(m0 + r) * 1024 + k0 + gcS], &Xh[wave * 32 + tt * 16][0]);
            async16(&xl[(size_t)(m0 + r) * 1024 + k0 + gcS], &Xl[wave * 32 + tt * 16][0]);
            if constexpr (PRE)
                async16(&WT[(size_t)(n0 + r) * 1024 + k0 + gcS], &Wf[wave * 32 + tt * 16][0]);
        }
        if constexpr (!PRE) {
            const size_t wb = (size_t)(k0 + wkb * 4) * 1024 + n0 + wn4;
            const float4 v0 = *(const float4*)&W[wb];
            const float4 v1 = *(const float4*)&W[wb + 1024];
            const float4 v2 = *(const float4*)&W[wb + 2048];
            const float4 v3 = *(const float4*)&W[wb + 3072];
            const float rv[4][4] = {{v0.x, v0.y, v0.z, v0.w},
                                    {v1.x, v1.y, v1.z, v1.w},
                                    {v2.x, v2.y, v2.z, v2.w},
                                    {v3.x, v3.y, v3.z, v3.w}};
            #pragma unroll
            for (int j = 0; j < 4; ++j) {
                const int R = wn4 + j;
                const f16x4 hv = {(_Float16)rv[0][j], (_Float16)rv[1][j],
                                  (_Float16)rv[2][j], (_Float16)rv[3][j]};
                const int c = (wkb >> 1) ^ ((R >> 1) & 3);
                *(f16x4*)&Wf[R][c * 8 + (wkb & 1) * 4] = hv;
            }
        }
    };

    STAGE(0, 0);
    STAGE(1, 1);
    STAGE(2, 2);

    int bi = 0;
    for (int t = 0; t < 32; ++t) {
        if (t < 30)       { if constexpr (PRE) WAIT_VM(12); else WAIT_VM(8); }
        else if (t == 30) { if constexpr (PRE) WAIT_VM(6);  else WAIT_VM(4); }
        else              { WAIT_VM(0); }
        __builtin_amdgcn_s_barrier();

        _Float16 (*Xh)[32] = (_Float16(*)[32])(psm + bi * 24576);
        _Float16 (*Xl)[32] = (_Float16(*)[32])(psm + bi * 24576 + 8192);
        _Float16 (*Wf)[32] = (_Float16(*)[32])(psm + bi * 24576 + 16384);
        f16x8 ah[4], al[4], bfv[4];
        #pragma unroll
        for (int f = 0; f < 4; ++f) {
            ah[f]  = *(const f16x8*)&Xh[wm + f * 16 + ar][qs];
            al[f]  = *(const f16x8*)&Xl[wm + f * 16 + ar][qs];
            bfv[f] = *(const f16x8*)&Wf[wn + f * 16 + ar][qs];
        }
        #pragma unroll
        for (int i = 0; i < 4; ++i)
            #pragma unroll
            for (int j = 0; j < 4; ++j) {
                acc[i][j] = MFMA_F16(ah[i], bfv[j], acc[i][j]);
                acc[i][j] = MFMA_F16(al[i], bfv[j], acc[i][j]);
            }
        __builtin_amdgcn_s_barrier();

        if (t < 29) {
            STAGE(t + 3, bi);
            if constexpr (!PRE)
                asm volatile("s_waitcnt lgkmcnt(0)" ::: "memory");
        }
        bi = (bi == 2) ? 0 : bi + 1;
    }

    // epilogue: acc -> LDS (h/l interleaved row segments) -> coalesced stores
    _Float16* Ep = (_Float16*)psm;
    const int q4 = (lane >> 4) * 4;
    #pragma unroll
    for (int j = 0; j < 4; ++j) {
        const int nloc = wn + j * 16 + ar;
        const float bv = bias[n0 + nloc];
        const int nidx = (nloc >> 3) * 16 + (nloc & 7);
        #pragma unroll
        for (int i = 0; i < 4; ++i)
            #pragma unroll
            for (int r = 0; r < 4; ++r) {
                const int Rl = wm + i * 16 + q4 + r;
                const float v = acc[i][j][r] + bv;
                const _Float16 h = (_Float16)v;
                Ep[Rl * 256 + nidx]     = h;
                Ep[Rl * 256 + nidx + 8] = (_Float16)(v - (float)h);
            }
    }
    __syncthreads();
    #pragma unroll
    for (int c = 0; c < 16; ++c) {
        const int lin = c * 4096 + tid * 16;
        const int row = lin >> 9;
        const int off = lin & 511;
        *(float4*)(outc + (size_t)(m0 + row) * 4096 + n0 * 4 + off)
            = *(const float4*)(psm + lin);
    }
}

// ================= K2: attention per (batch, 64 sx rows), fp16 ==============
// R2 structure (211us best-measured): col-split waves; per-wave LDS stripe
// staged 1 iteration ahead; WAIT_VM(0)/LGKM(0) per kk; A-frags direct from
// global (interleaved h/l layout). Phase 2: Yt stripe staged per k-step.
__global__ __launch_bounds__(256, 2)
void attn_f16_kernel(const _Float16* __restrict__ yf, const _Float16* __restrict__ yT,
                     char* __restrict__ outc)
{
    __shared__ __align__(16) char smem[76800];
    _Float16 (*Yst)[32]   = (_Float16(*)[32])smem;            // [512][32] phase 0
    _Float16 (*Pbuf)[520] = (_Float16(*)[520])smem;           // [64][520] ph 1/2 overlay
    _Float16 (*Yt)[32]    = (_Float16(*)[32])(smem + 66560);  // [128][32] phase 2
    float*    Red         = (float*)(smem + 74752);           // [512]

    const int tid = threadIdx.x, lane = tid & 63, wave = tid >> 6;
    const int swzb = (blockIdx.x & 7) * 64 + (blockIdx.x >> 3);
    const int b = swzb >> 3, sx0 = (swzb & 7) * 64;
    const int pbase = b * 512 + sx0;
    const int ar = lane & 15, q = lane >> 4, qk = q * 8;
    const int qs  = (q ^ ((lane >> 1) & 3)) * 8;              // swizzled frag col
    const int gcS = ((lane & 3) ^ ((lane >> 3) & 3)) * 8;     // swizzled stage col
    const int lrow = lane >> 2;
    const size_t ybase = (size_t)b * 512 * 1024;

    // ---- phase 0: S = proj @ y^T, wave w -> sy cols [128w, 128w+128) ----
    f32x4 s2[4][8];
    #pragma unroll
    for (int ri = 0; ri < 4; ++ri)
        #pragma unroll
        for (int t = 0; t < 8; ++t)
            s2[ri][t] = (f32x4){0.f, 0.f, 0.f, 0.f};

    const char* aptr = outc + (size_t)(pbase + ar) * 4096;    // + ri*65536

    // prologue: stage kk=0 into own stripe, load A(0)
    #pragma unroll
    for (int t = 0; t < 8; ++t) {
        const int r = wave * 128 + t * 16 + lrow;
        async16(&yf[ybase + (size_t)r * 1024 + gcS], &Yst[wave * 128 + t * 16][0]);
    }
    f16x8 aH[4], aL[4];
    #pragma unroll
    for (int ri = 0; ri < 4; ++ri) {
        const char* p = aptr + (size_t)ri * 65536 + (size_t)q * 32;
        aH[ri] = *(const f16x8*)p;
        aL[ri] = *(const f16x8*)(p + 16);
    }

    for (int kk = 0; kk < 32; ++kk) {
        WAIT_VM(0);                               // stage(kk) + A(kk) landed
        f16x8 bf0[8];
        #pragma unroll
        for (int t = 0; t < 8; ++t)
            bf0[t] = *(const f16x8*)&Yst[wave * 128 + t * 16 + ar][qs];
        WAIT_LGKM0();                             // frags in regs; stripe reusable
        if (kk < 31) {
            const int k1 = (kk + 1) * 32;
            #pragma unroll
            for (int t = 0; t < 8; ++t) {
                const int r = wave * 128 + t * 16 + lrow;
                async16(&yf[ybase + (size_t)r * 1024 + k1 + gcS],
                        &Yst[wave * 128 + t * 16][0]);
            }
        }
        #pragma unroll
        for (int ri = 0; ri < 4; ++ri)
            #pragma unroll
            for (int t = 0; t < 8; ++t) {
                s2[ri][t] = MFMA_F16(aH[ri], bf0[t], s2[ri][t]);
                s2[ri][t] = MFMA_F16(aL[ri], bf0[t], s2[ri][t]);
            }
        if (kk < 31) {
            #pragma unroll
            for (int ri = 0; ri < 4; ++ri) {
                const char* p = aptr + (size_t)ri * 65536
                              + (size_t)((kk + 1) * 4 + q) * 32;
                aH[ri] = *(const f16x8*)p;
                aL[ri] = *(const f16x8*)(p + 16);
            }
        }
    }

    // ---- phase 1: softmax, cross-wave combine via Red ----
    float pm[4][4];
    #pragma unroll
    for (int ri = 0; ri < 4; ++ri)
        #pragma unroll
        for (int r = 0; r < 4; ++r) {
            float m = -3.0e38f;
            #pragma unroll
            for (int t = 0; t < 8; ++t) m = fmaxf(m, s2[ri][t][r]);
            pm[ri][r] = m;
        }
    #pragma unroll
    for (int off = 1; off < 16; off <<= 1)
        #pragma unroll
        for (int ri = 0; ri < 4; ++ri)
            #pragma unroll
            for (int r = 0; r < 4; ++r)
                pm[ri][r] = fmaxf(pm[ri][r], __shfl_xor(pm[ri][r], off, 64));
    if (ar == 0) {
        #pragma unroll
        for (int ri = 0; ri < 4; ++ri)
            #pragma unroll
            for (int r = 0; r < 4; ++r)
                Red[wave * 64 + ri * 16 + q * 4 + r] = pm[ri][r];
    }
    __syncthreads();   // (1) maxes visible; all Yst reads complete
    float gm[4][4];
    #pragma unroll
    for (int ri = 0; ri < 4; ++ri)
        #pragma unroll
        for (int r = 0; r < 4; ++r) {
            const int row = ri * 16 + q * 4 + r;
            gm[ri][r] = fmaxf(fmaxf(Red[row], Red[64 + row]),
                              fmaxf(Red[128 + row], Red[192 + row]));
        }
    float ps[4][4];
    #pragma unroll
    for (int ri = 0; ri < 4; ++ri)
        #pragma unroll
        for (int r = 0; r < 4; ++r) {
            float sum = 0.f;
            #pragma unroll
            for (int t = 0; t < 8; ++t) {
                const float e = __expf(s2[ri][t][r] - gm[ri][r]);
                s2[ri][t][r] = e;
                sum += e;
            }
            ps[ri][r] = sum;
        }
    #pragma unroll
    for (int off = 1; off < 16; off <<= 1)
        #pragma unroll
        for (int ri = 0; ri < 4; ++ri)
            #pragma unroll
            for (int r = 0; r < 4; ++r)
                ps[ri][r] += __shfl_xor(ps[ri][r], off, 64);
    if (ar == 0) {
        #pragma unroll
        for (int ri = 0; ri < 4; ++ri)
            #pragma unroll
            for (int r = 0; r < 4; ++r)
                Red[256 + wave * 64 + ri * 16 + q * 4 + r] = ps[ri][r];
    }
    __syncthreads();   // (2) sums visible
    float inv[4][4];
    #pragma unroll
    for (int ri = 0; ri < 4; ++ri)
        #pragma unroll
        for (int r = 0; r < 4; ++r) {
            const int row = 256 + ri * 16 + q * 4 + r;
            inv[ri][r] = 1.0f / (Red[row] + Red[64 + row] + Red[128 + row] + Red[192 + row]);
        }
    #pragma unroll
    for (int ri = 0; ri < 4; ++ri)
        #pragma unroll
        for (int t = 0; t < 8; ++t)
            #pragma unroll
            for (int r = 0; r < 4; ++r)
                Pbuf[ri * 16 + q * 4 + r][wave * 128 + t * 16 + ar]
                    = (_Float16)(s2[ri][t][r] * inv[ri][r]);
    __syncthreads();   // (3) Pbuf complete before phase-2 reads

    // ---- phase 2: O = P @ y via yT; wave w -> d cols [dc*128+32w, +32) ----
    float* outF = (float*)outc;
    for (int dc = 0; dc < 8; ++dc) {
        f32x4 o2[4][2];
        #pragma unroll
        for (int ri = 0; ri < 4; ++ri)
            #pragma unroll
            for (int t = 0; t < 2; ++t)
                o2[ri][t] = (f32x4){0.f, 0.f, 0.f, 0.f};

        WAIT_LGKM0();   // prev-dc stripe reads done before overwrite
        #pragma unroll
        for (int t = 0; t < 2; ++t) {
            const int r = wave * 32 + t * 16 + lrow;
            async16(&yT[(size_t)(b * 1024 + dc * 128 + r) * 512 + gcS],
                    &Yt[wave * 32 + t * 16][0]);
        }
        for (int kk = 0; kk < 16; ++kk) {
            WAIT_VM(0);
            f16x8 a2[4], b2[2];
            #pragma unroll
            for (int ri = 0; ri < 4; ++ri)
                a2[ri] = *(const f16x8*)&Pbuf[ri * 16 + ar][kk * 32 + qk];
            #pragma unroll
            for (int t = 0; t < 2; ++t)
                b2[t] = *(const f16x8*)&Yt[wave * 32 + t * 16 + ar][qs];
            WAIT_LGKM0();
            if (kk < 15) {
                const int k1 = (kk + 1) * 32;
                #pragma unroll
                for (int t = 0; t < 2; ++t) {
                    const int r = wave * 32 + t * 16 + lrow;
                    async16(&yT[(size_t)(b * 1024 + dc * 128 + r) * 512 + k1 + gcS],
                            &Yt[wave * 32 + t * 16][0]);
                }
            }
            #pragma unroll
            for (int ri = 0; ri < 4; ++ri)
                #pragma unroll
                for (int t = 0; t < 2; ++t)
                    o2[ri][t] = MFMA_F16(a2[ri], b2[t], o2[ri][t]);
        }
        #pragma unroll
        for (int ri = 0; ri < 4; ++ri)
            #pragma unroll
            for (int t = 0; t < 2; ++t)
                #pragma unroll
                for (int r = 0; r < 4; ++r)
                    outF[(size_t)(pbase + ri * 16 + q * 4 + r) * 1024
                         + dc * 128 + wave * 32 + t * 16 + ar] = o2[ri][t][r];
    }
}

// ===================== fallback path (round-1, known good) ==================

__device__ __forceinline__ void cvt4(const float4 v, bf16x4& h, bf16x4& l) {
    const float f0 = v.x, f1 = v.y, f2 = v.z, f3 = v.w;
    const __bf16 h0 = (__bf16)f0, h1 = (__bf16)f1, h2 = (__bf16)f2, h3 = (__bf16)f3;
    h = (bf16x4){h0, h1, h2, h3};
    l = (bf16x4){(__bf16)(f0 - (float)h0), (__bf16)(f1 - (float)h1),
                 (__bf16)(f2 - (float)h2), (__bf16)(f3 - (float)h3)};
}

__global__ __launch_bounds__(256, 2)
void proj_kernel_fb(const float* __restrict__ x, const float* __restrict__ W,
                    const float* __restrict__ bias, float* __restrict__ proj)
{
    __shared__ __bf16 Ah[128][40];
    __shared__ __bf16 Al[128][40];
    __shared__ __bf16 Bh[128][40];
    __shared__ __bf16 Bl[128][40];

    const int tid = threadIdx.x, lane = tid & 63, wave = tid >> 6;
    const int wm = (wave >> 1) * 64, wn = (wave & 1) * 64;
    const int m0 = (blockIdx.x >> 3) * 128, n0 = (blockIdx.x & 7) * 128;
    const int ar = lane & 15, ak = (lane >> 4) * 8;

    f32x4 acc[4][4];
    #pragma unroll
    for (int i = 0; i < 4; ++i)
        #pragma unroll
        for (int j = 0; j < 4; ++j)
            acc[i][j] = (f32x4){0.f, 0.f, 0.f, 0.f};

    const int xr = tid >> 3, xc = (tid & 7) * 4;
    const int wkb = tid >> 5, wn4 = (tid & 31) * 4;

    for (int k0 = 0; k0 < 1024; k0 += 32) {
        __syncthreads();
        #pragma unroll
        for (int it = 0; it < 4; ++it) {
            const int r = xr + it * 32;
            const float4 v = *(const float4*)&x[(size_t)(m0 + r) * 1024 + k0 + xc];
            bf16x4 h, l; cvt4(v, h, l);
            *(bf16x4*)&Ah[r][xc] = h;
            *(bf16x4*)&Al[r][xc] = l;
        }
        {
            const size_t wb = (size_t)(k0 + wkb * 4) * 1024 + n0 + wn4;
            const float4 v0 = *(const float4*)&W[wb];
            const float4 v1 = *(const float4*)&W[wb + 1024];
            const float4 v2 = *(const float4*)&W[wb + 2048];
            const float4 v3 = *(const float4*)&W[wb + 3072];
            const float rv[4][4] = {{v0.x, v0.y, v0.z, v0.w},
                                    {v1.x, v1.y, v1.z, v1.w},
                                    {v2.x, v2.y, v2.z, v2.w},
                                    {v3.x, v3.y, v3.z, v3.w}};
            #pragma unroll
            for (int j = 0; j < 4; ++j) {
                bf16x4 h, l;
                #pragma unroll
                for (int kk = 0; kk < 4; ++kk) {
                    const float f = rv[kk][j];
                    const __bf16 hb = (__bf16)f;
                    h[kk] = hb;
                    l[kk] = (__bf16)(f - (float)hb);
                }
                *(bf16x4*)&Bh[wn4 + j][wkb * 4] = h;
                *(bf16x4*)&Bl[wn4 + j][wkb * 4] = l;
            }
        }
        __syncthreads();

        bf16x8 a_h[4], a_l[4], b_h[4], b_l[4];
        #pragma unroll
        for (int f = 0; f < 4; ++f) {
            a_h[f] = *(const bf16x8*)&Ah[wm + f * 16 + ar][ak];
            a_l[f] = *(const bf16x8*)&Al[wm + f * 16 + ar][ak];
            b_h[f] = *(const bf16x8*)&Bh[wn + f * 16 + ar][ak];
            b_l[f] = *(const bf16x8*)&Bl[wn + f * 16 + ar][ak];
        }
        #pragma unroll
        for (int i = 0; i < 4; ++i)
            #pragma unroll
            for (int j = 0; j < 4; ++j) {
                acc[i][j] = MFMA_BF16(a_h[i], b_h[j], acc[i][j]);
                acc[i][j] = MFMA_BF16(a_l[i], b_h[j], acc[i][j]);
                acc[i][j] = MFMA_BF16(a_h[i], b_l[j], acc[i][j]);
            }
    }

    const int q4 = (lane >> 4) * 4;
    #pragma unroll
    for (int j = 0; j < 4; ++j) {
        const int n = n0 + wn + j * 16 + ar;
        const float bv = bias[n];
        #pragma unroll
        for (int i = 0; i < 4; ++i) {
            const size_t base = (size_t)(m0 + wm + i * 16 + q4) * 1024 + n;
            #pragma unroll
            for (int r = 0; r < 4; ++r)
                proj[base + (size_t)r * 1024] = acc[i][j][r] + bv;
        }
    }
}

__global__ __launch_bounds__(256, 1)
void attn_kernel_fb(const float* __restrict__ y, float* __restrict__ out)
{
    __shared__ __bf16 Ph[64][40];
    __shared__ __bf16 Pl[64][40];
    __shared__ __bf16 Yh[128][40];
    __shared__ __bf16 Yl[128][40];
    __shared__ __bf16 Pbuf[64][520];

    const int tid = threadIdx.x, lane = tid & 63, wave = tid >> 6;
    const int b = blockIdx.x >> 3, sx0 = (blockIdx.x & 7) * 64;
    const size_t ybase = (size_t)b * 512 * 1024;
    const size_t pbase = ((size_t)b * 512 + sx0) * 1024;
    const int ar = lane & 15, ak = (lane >> 4) * 8, q = lane >> 4;

    f32x4 s[4][8];
    #pragma unroll
    for (int nb = 0; nb < 4; ++nb)
        #pragma unroll
        for (int f = 0; f < 8; ++f)
            s[nb][f] = (f32x4){0.f, 0.f, 0.f, 0.f};

    const int pr = tid >> 3, pc = (tid & 7) * 4;

    for (int k0 = 0; k0 < 1024; k0 += 32) {
        __syncthreads();
        #pragma unroll
        for (int it = 0; it < 2; ++it) {
            const int r = pr + it * 32;
            const float4 v = *(const float4*)&out[pbase + (size_t)r * 1024 + k0 + pc];
            bf16x4 h, l; cvt4(v, h, l);
            *(bf16x4*)&Ph[r][pc] = h;
            *(bf16x4*)&Pl[r][pc] = l;
        }
        #pragma unroll
        for (int nb = 0; nb < 4; ++nb) {
            if (nb) __syncthreads();
            const int sy0 = nb * 128;
            #pragma unroll
            for (int it = 0; it < 4; ++it) {
                const int r = pr + it * 32;
                const float4 v = *(const float4*)&y[ybase + (size_t)(sy0 + r) * 1024 + k0 + pc];
                bf16x4 h, l; cvt4(v, h, l);
                *(bf16x4*)&Yh[r][pc] = h;
                *(bf16x4*)&Yl[r][pc] = l;
            }
            __syncthreads();
            const bf16x8 a_h = *(const bf16x8*)&Ph[wave * 16 + ar][ak];
            const bf16x8 a_l = *(const bf16x8*)&Pl[wave * 16 + ar][ak];
            #pragma unroll
            for (int f = 0; f < 8; ++f) {
                const bf16x8 b_h = *(const bf16x8*)&Yh[f * 16 + ar][ak];
                const bf16x8 b_l = *(const bf16x8*)&Yl[f * 16 + ar][ak];
                s[nb][f] = MFMA_BF16(a_h, b_h, s[nb][f]);
                s[nb][f] = MFMA_BF16(a_l, b_h, s[nb][f]);
                s[nb][f] = MFMA_BF16(a_h, b_l, s[nb][f]);
            }
        }
    }

    #pragma unroll
    for (int r = 0; r < 4; ++r) {
        float m = -3.0e38f;
        #pragma unroll
        for (int nb = 0; nb < 4; ++nb)
            #pragma unroll
            for (int f = 0; f < 8; ++f)
                m = fmaxf(m, s[nb][f][r]);
        #pragma unroll
        for (int off = 1; off < 16; off <<= 1)
            m = fmaxf(m, __shfl_xor(m, off, 64));
        float sum = 0.f;
        #pragma unroll
        for (int nb = 0; nb < 4; ++nb)
            #pragma unroll
            for (int f = 0; f < 8; ++f) {
                const float e = __expf(s[nb][f][r] - m);
                s[nb][f][r] = e;
                sum += e;
            }
        #pragma unroll
        for (int off = 1; off < 16; off <<= 1)
            sum += __shfl_xor(sum, off, 64);
        const float inv = 1.0f / sum;
        #pragma unroll
        for (int nb = 0; nb < 4; ++nb)
            #pragma unroll
            for (int f = 0; f < 8; ++f)
                s[nb][f][r] *= inv;
    }
    #pragma unroll
    for (int nb = 0; nb < 4; ++nb)
        #pragma unroll
        for (int f = 0; f < 8; ++f)
            #pragma unroll
            for (int r = 0; r < 4; ++r)
                Pbuf[wave * 16 + q * 4 + r][nb * 128 + f * 16 + ar] = (__bf16)s[nb][f][r];

    const int y2kb = tid >> 5, y2n4 = (tid & 31) * 4;
    for (int d0 = 0; d0 < 1024; d0 += 128) {
        f32x4 o[8];
        #pragma unroll
        for (int f = 0; f < 8; ++f) o[f] = (f32x4){0.f, 0.f, 0.f, 0.f};

        for (int k0 = 0; k0 < 512; k0 += 32) {
            __syncthreads();
            const size_t yb = ybase + (size_t)(k0 + y2kb * 4) * 1024 + d0 + y2n4;
            const float4 v0 = *(const float4*)&y[yb];
            const float4 v1 = *(const float4*)&y[yb + 1024];
            const float4 v2 = *(const float4*)&y[yb + 2048];
            const float4 v3 = *(const float4*)&y[yb + 3072];
            const float rv[4][4] = {{v0.x, v0.y, v0.z, v0.w},
                                    {v1.x, v1.y, v1.z, v1.w},
                                    {v2.x, v2.y, v2.z, v2.w},
                                    {v3.x, v3.y, v3.z, v3.w}};
            #pragma unroll
            for (int j = 0; j < 4; ++j) {
                const bf16x4 h = (bf16x4){(__bf16)rv[0][j], (__bf16)rv[1][j],
                                          (__bf16)rv[2][j], (__bf16)rv[3][j]};
                *(bf16x4*)&Yh[y2n4 + j][y2kb * 4] = h;
            }
            __syncthreads();
            const bf16x8 a = *(const bf16x8*)&Pbuf[wave * 16 + ar][k0 + ak];
            #pragma unroll
            for (int f = 0; f < 8; ++f) {
                const bf16x8 bb = *(const bf16x8*)&Yh[f * 16 + ar][ak];
                o[f] = MFMA_BF16(a, bb, o[f]);
            }
        }
        #pragma unroll
        for (int f = 0; f < 8; ++f)
            #pragma unroll
            for (int r = 0; r < 4; ++r)
                out[pbase + (size_t)(wave * 16 + q * 4 + r) * 1024 + d0 + f * 16 + ar] = o[f][r];
    }
}

// ============================== launch ======================================

extern "C" void kernel_launch(void* const* d_in, const int* in_sizes, int n_in,
                              void* d_out, int out_size, void* d_ws, size_t ws_size,
                              hipStream_t stream) {
    (void)in_sizes; (void)n_in; (void)out_size;
    const float* x    = (const float*)d_in[0];
    const float* y    = (const float*)d_in[1];
    const float* W    = (const float*)d_in[2];
    const float* bias = (const float*)d_in[3];

    if (ws_size >= 268435456ULL) {
        _Float16* yf = (_Float16*)d_ws;
        _Float16* yT = yf + 33554432;
        _Float16* xh = yT + 33554432;
        _Float16* xl = xh + 33554432;
        _Float16* WT = xl + 33554432;
        const bool pre = ws_size >= 268435456ULL + 2097152ULL;

        if (pre) {
            prep_all_kernel<true><<<dim3(10496), dim3(256), 0, stream>>>(
                y, yf, yT, x, (f16x4*)xh, (f16x4*)xl, W, WT);
            proj_f16_kernel<true><<<dim3(2048), dim3(256), 0, stream>>>(xh, xl, WT, W, bias,
                                                                        (char*)d_out);
        } else {
            prep_all_kernel<false><<<dim3(10240), dim3(256), 0, stream>>>(
                y, yf, yT, x, (f16x4*)xh, (f16x4*)xl, W, nullptr);
            proj_f16_kernel<false><<<dim3(2048), dim3(256), 0, stream>>>(xh, xl, nullptr, W,
                                                                         bias, (char*)d_out);
        }
        attn_f16_kernel<<<dim3(512), dim3(256), 0, stream>>>(yf, yT, (char*)d_out);
    } else {
        float* out = (float*)d_out;
        proj_kernel_fb<<<dim3(256 * 8), dim3(256), 0, stream>>>(x, W, bias, out);
        attn_kernel_fb<<<dim3(64 * 8), dim3(256), 0, stream>>>(y, out);
    }
}

// Round 12
// 678.570 us; speedup vs baseline: 1.0972x; 1.0154x over previous
//
#include <hip/hip_runtime.h>

// ESIM layer: out = softmax((x@W + b) @ y^T) @ y
// B=64, Sx=Sy=512, D=1024, fp32 in/out.
//
// Round-13:
//  * proj: triple-buffer (72KB, 2 blk/CU) -> DOUBLE-buffer (48KB, 3 blk/CU,
//    3 waves/SIMD = +50% TLP). Counted vmcnt keeps 1 tile in flight
//    (vmcnt(6)/(4), never 0 mid-loop; stage->use distance 2 K-steps).
//    Epilogue split into 2 half-passes (32KB each) to fit 48KB LDS.
//  * attn: R11 verbatim (211us reproducible optimum; ledger closed after
//    7 failed restructures + null setprio).
//  * prep: merged kernel (kept).

typedef float  f32x4  __attribute__((ext_vector_type(4)));
typedef _Float16 f16x8 __attribute__((ext_vector_type(8)));
typedef _Float16 f16x4 __attribute__((ext_vector_type(4)));
typedef __bf16 bf16x8 __attribute__((ext_vector_type(8)));
typedef __bf16 bf16x4 __attribute__((ext_vector_type(4)));

#define MFMA_F16(a, b, c)  __builtin_amdgcn_mfma_f32_16x16x32_f16((a), (b), (c), 0, 0, 0)
#define MFMA_BF16(a, b, c) __builtin_amdgcn_mfma_f32_16x16x32_bf16((a), (b), (c), 0, 0, 0)

#define WAIT_VM(N)  do { asm volatile("s_waitcnt vmcnt(" #N ")" ::: "memory"); \
                         __builtin_amdgcn_sched_barrier(0); } while (0)
#define WAIT_LGKM0() do { asm volatile("s_waitcnt lgkmcnt(0)" ::: "memory"); \
                          __builtin_amdgcn_sched_barrier(0); } while (0)

__device__ __forceinline__ void async16(const void* g, void* lds) {
    __builtin_amdgcn_global_load_lds(
        (const __attribute__((address_space(1))) unsigned int*)g,
        (__attribute__((address_space(3))) unsigned int*)lds, 16, 0, 0);
}

// ========================= merged prep kernel ===============================
template <bool DOW>
__global__ void prep_all_kernel(const float* __restrict__ y, _Float16* __restrict__ yf,
                                _Float16* __restrict__ yT, const float* __restrict__ x,
                                f16x4* __restrict__ xh, f16x4* __restrict__ xl,
                                const float* __restrict__ W, _Float16* __restrict__ WT)
{
    __shared__ _Float16 LT[64][72];
    const int tid = threadIdx.x;
    const int bid = blockIdx.x;

    if (bid < 8192) {
        const int b   = bid >> 7;
        const int rem = bid & 127;
        const int sy0 = (rem >> 4) * 64;
        const int d0  = (rem & 15) * 64;
        const int r0 = tid >> 4;
        const int c4 = (tid & 15) * 4;
        #pragma unroll
        for (int i = 0; i < 4; ++i) {
            const int r = r0 + i * 16;
            const float4 v = *(const float4*)&y[((size_t)b * 512 + sy0 + r) * 1024 + d0 + c4];
            const f16x4 hv = {(_Float16)v.x, (_Float16)v.y, (_Float16)v.z, (_Float16)v.w};
            *(f16x4*)&yf[((size_t)b * 512 + sy0 + r) * 1024 + d0 + c4] = hv;
            #pragma unroll
            for (int cc = 0; cc < 4; ++cc) {
                const int c = (cc + (tid & 3)) & 3;
                LT[c4 + c][r] = hv[c];
            }
        }
        __syncthreads();
        #pragma unroll
        for (int i = 0; i < 4; ++i) {
            const int dr = r0 + i * 16;
            const f16x4 v = *(const f16x4*)&LT[dr][(tid & 15) * 4];
            *(f16x4*)&yT[((size_t)b * 1024 + d0 + dr) * 512 + sy0 + (tid & 15) * 4] = v;
        }
    } else if (bid < 10240) {
        int i = (bid - 8192) * 256 + tid;
        const float4* in = (const float4*)x;
        for (; i < 8388608; i += 2048 * 256) {
            const float4 v = in[i];
            const _Float16 h0 = (_Float16)v.x, h1 = (_Float16)v.y,
                           h2 = (_Float16)v.z, h3 = (_Float16)v.w;
            xh[i] = (f16x4){h0, h1, h2, h3};
            xl[i] = (f16x4){(_Float16)(v.x - (float)h0), (_Float16)(v.y - (float)h1),
                            (_Float16)(v.z - (float)h2), (_Float16)(v.w - (float)h3)};
        }
    } else if constexpr (DOW) {
        const int rem = bid - 10240;
        const int k0 = (rem >> 4) * 64;
        const int n0 = (rem & 15) * 64;
        const int r0 = tid >> 4;
        const int c4 = (tid & 15) * 4;
        #pragma unroll
        for (int i = 0; i < 4; ++i) {
            const int r = r0 + i * 16;
            const float4 v = *(const float4*)&W[(size_t)(k0 + r) * 1024 + n0 + c4];
            const f16x4 hv = {(_Float16)v.x, (_Float16)v.y, (_Float16)v.z, (_Float16)v.w};
            #pragma unroll
            for (int cc = 0; cc < 4; ++cc) {
                const int c = (cc + (tid & 3)) & 3;
                LT[c4 + c][r] = hv[c];
            }
        }
        __syncthreads();
        #pragma unroll
        for (int i = 0; i < 4; ++i) {
            const int dr = r0 + i * 16;
            const f16x4 v = *(const f16x4*)&LT[dr][(tid & 15) * 4];
            *(f16x4*)&WT[(size_t)(n0 + dr) * 1024 + k0 + (tid & 15) * 4] = v;
        }
    }
}

// ===================== K1: proj = x@W + b (fp16 2-term) =====================
// 128x128 tile, BK=32, 4 waves. DOUBLE-buffer LDS (48KB -> 3 blocks/CU) +
// raw s_barrier + counted vmcnt (1 tile in flight; vmcnt(6)/(4) mid-loop).
// Row slot (4KB/row): per 8-half group g: h at g*32B, l at g*32+16.
template <bool PRE>
__global__ __launch_bounds__(256, 3)
void proj_f16_kernel(const _Float16* __restrict__ xh, const _Float16* __restrict__ xl,
                     const _Float16* __restrict__ WT, const float* __restrict__ W,
                     const float* __restrict__ bias, char* __restrict__ outc)
{
    __shared__ __align__(16) char psm[49152];   // 2 bufs x (Xh 8K | Xl 8K | Wf 8K)

    const int tid = threadIdx.x, lane = tid & 63, wave = tid >> 6;
    const int swz = (blockIdx.x & 7) * 256 + (blockIdx.x >> 3);
    const int m0 = (swz >> 3) * 128, n0 = (swz & 7) * 128;
    const int wm = (wave >> 1) * 64, wn = (wave & 1) * 64;
    const int ar = lane & 15;
    const int qs  = ((lane >> 4) ^ ((lane >> 1) & 3)) * 8;
    const int gcS = ((lane & 3) ^ ((lane >> 3) & 3)) * 8;
    const int lrow = lane >> 2;
    const int wkb = tid & 7;
    const int wn4 = (tid >> 3) * 4;

    f32x4 acc[4][4];
    #pragma unroll
    for (int i = 0; i < 4; ++i)
        #pragma unroll
        for (int j = 0; j < 4; ++j)
            acc[i][j] = (f32x4){0.f, 0.f, 0.f, 0.f};

    auto STAGE = [&](int t, int bi) {
        const int k0 = t * 32;
        _Float16 (*Xh)[32] = (_Float16(*)[32])(psm + bi * 24576);
        _Float16 (*Xl)[32] = (_Float16(*)[32])(psm + bi * 24576 + 8192);
        _Float16 (*Wf)[32] = (_Float16(*)[32])(psm + bi * 24576 + 16384);
        #pragma unroll
        for (int tt = 0; tt < 2; ++tt) {
            const int r = wave * 32 + tt * 16 + lrow;
            async16(&xh[(size_t)(m0 + r) * 1024 + k0 + gcS], &Xh[wave * 32 + tt * 16][0]);
            async16(&xl[(size_t)(m0 + r) * 1024 + k0 + gcS], &Xl[wave * 32 + tt * 16][0]);
            if constexpr (PRE)
                async16(&WT[(size_t)(n0 + r) * 1024 + k0 + gcS], &Wf[wave * 32 + tt * 16][0]);
        }
        if constexpr (!PRE) {
            const size_t wb = (size_t)(k0 + wkb * 4) * 1024 + n0 + wn4;
            const float4 v0 = *(const float4*)&W[wb];
            const float4 v1 = *(const float4*)&W[wb + 1024];
            const float4 v2 = *(const float4*)&W[wb + 2048];
            const float4 v3 = *(const float4*)&W[wb + 3072];
            const float rv[4][4] = {{v0.x, v0.y, v0.z, v0.w},
                                    {v1.x, v1.y, v1.z, v1.w},
                                    {v2.x, v2.y, v2.z, v2.w},
                                    {v3.x, v3.y, v3.z, v3.w}};
            #pragma unroll
            for (int j = 0; j < 4; ++j) {
                const int R = wn4 + j;
                const f16x4 hv = {(_Float16)rv[0][j], (_Float16)rv[1][j],
                                  (_Float16)rv[2][j], (_Float16)rv[3][j]};
                const int c = (wkb >> 1) ^ ((R >> 1) & 3);
                *(f16x4*)&Wf[R][c * 8 + (wkb & 1) * 4] = hv;
            }
        }
    };

    // prologue: 2 tiles in flight
    STAGE(0, 0);
    STAGE(1, 1);

    for (int t = 0; t < 32; ++t) {
        const int bi = t & 1;
        // wait own tile-t asyncs (FIFO: leave 1 newest tile = 6/4 pending)
        if (t < 31) { if constexpr (PRE) WAIT_VM(6); else WAIT_VM(4); }
        else        { WAIT_VM(0); }
        __builtin_amdgcn_s_barrier();   // rendezvous: everyone's tile-t landed

        _Float16 (*Xh)[32] = (_Float16(*)[32])(psm + bi * 24576);
        _Float16 (*Xl)[32] = (_Float16(*)[32])(psm + bi * 24576 + 8192);
        _Float16 (*Wf)[32] = (_Float16(*)[32])(psm + bi * 24576 + 16384);
        f16x8 ah[4], al[4], bfv[4];
        #pragma unroll
        for (int f = 0; f < 4; ++f) {
            ah[f]  = *(const f16x8*)&Xh[wm + f * 16 + ar][qs];
            al[f]  = *(const f16x8*)&Xl[wm + f * 16 + ar][qs];
            bfv[f] = *(const f16x8*)&Wf[wn + f * 16 + ar][qs];
        }
        #pragma unroll
        for (int i = 0; i < 4; ++i)
            #pragma unroll
            for (int j = 0; j < 4; ++j) {
                acc[i][j] = MFMA_F16(ah[i], bfv[j], acc[i][j]);
                acc[i][j] = MFMA_F16(al[i], bfv[j], acc[i][j]);
            }
        __builtin_amdgcn_s_barrier();   // all reads of buf bi done

        if (t < 30) {
            STAGE(t + 2, bi);           // refill the buffer just consumed
            if constexpr (!PRE)
                asm volatile("s_waitcnt lgkmcnt(0)" ::: "memory");
        }
    }

    // ---- epilogue: 2 half-passes (32KB each): acc -> LDS -> coalesced out
    _Float16* Ep = (_Float16*)psm;      // [64 rows][256 f16] = 512B/row
    const int q4 = (lane >> 4) * 4;
    #pragma unroll
    for (int pass = 0; pass < 2; ++pass) {
        __syncthreads();                // psm free (k-loop done / pass-0 copied)
        if ((wave >> 1) == pass) {      // waves with wm == pass*64
            #pragma unroll
            for (int j = 0; j < 4; ++j) {
                const int nloc = wn + j * 16 + ar;
                const float bv = bias[n0 + nloc];
                const int nidx = (nloc >> 3) * 16 + (nloc & 7);
                #pragma unroll
                for (int i = 0; i < 4; ++i)
                    #pragma unroll
                    for (int r = 0; r < 4; ++r) {
                        const int Rl = i * 16 + q4 + r;   // 0..63 within half
                        const float v = acc[i][j][r] + bv;
                        const _Float16 h = (_Float16)v;
                        Ep[Rl * 256 + nidx]     = h;
                        Ep[Rl * 256 + nidx + 8] = (_Float16)(v - (float)h);
                    }
            }
        }
        __syncthreads();
        #pragma unroll
        for (int c = 0; c < 8; ++c) {   // 64 rows x 512B = 32KB out
            const int lin = c * 4096 + tid * 16;
            const int row = lin >> 9;
            const int off = lin & 511;
            *(float4*)(outc + (size_t)(m0 + pass * 64 + row) * 4096 + n0 * 4 + off)
                = *(const float4*)(psm + lin);
        }
    }
}

// ================= K2: attention per (batch, 64 sx rows), fp16 ==============
// R2/R11 structure (211us reproducible optimum): col-split waves; per-wave
// LDS stripe staged 1 iteration ahead; WAIT_VM(0)/LGKM(0) per kk; A-frags
// direct from global (interleaved h/l layout). Phase 2: Yt staged per k-step.
__global__ __launch_bounds__(256, 2)
void attn_f16_kernel(const _Float16* __restrict__ yf, const _Float16* __restrict__ yT,
                     char* __restrict__ outc)
{
    __shared__ __align__(16) char smem[76800];
    _Float16 (*Yst)[32]   = (_Float16(*)[32])smem;            // [512][32] phase 0
    _Float16 (*Pbuf)[520] = (_Float16(*)[520])smem;           // [64][520] ph 1/2 overlay
    _Float16 (*Yt)[32]    = (_Float16(*)[32])(smem + 66560);  // [128][32] phase 2
    float*    Red         = (float*)(smem + 74752);           // [512]

    const int tid = threadIdx.x, lane = tid & 63, wave = tid >> 6;
    const int swzb = (blockIdx.x & 7) * 64 + (blockIdx.x >> 3);
    const int b = swzb >> 3, sx0 = (swzb & 7) * 64;
    const int pbase = b * 512 + sx0;
    const int ar = lane & 15, q = lane >> 4, qk = q * 8;
    const int qs  = (q ^ ((lane >> 1) & 3)) * 8;              // swizzled frag col
    const int gcS = ((lane & 3) ^ ((lane >> 3) & 3)) * 8;     // swizzled stage col
    const int lrow = lane >> 2;
    const size_t ybase = (size_t)b * 512 * 1024;

    // ---- phase 0: S = proj @ y^T, wave w -> sy cols [128w, 128w+128) ----
    f32x4 s2[4][8];
    #pragma unroll
    for (int ri = 0; ri < 4; ++ri)
        #pragma unroll
        for (int t = 0; t < 8; ++t)
            s2[ri][t] = (f32x4){0.f, 0.f, 0.f, 0.f};

    const char* aptr = outc + (size_t)(pbase + ar) * 4096;    // + ri*65536

    // prologue: stage kk=0 into own stripe, load A(0)
    #pragma unroll
    for (int t = 0; t < 8; ++t) {
        const int r = wave * 128 + t * 16 + lrow;
        async16(&yf[ybase + (size_t)r * 1024 + gcS], &Yst[wave * 128 + t * 16][0]);
    }
    f16x8 aH[4], aL[4];
    #pragma unroll
    for (int ri = 0; ri < 4; ++ri) {
        const char* p = aptr + (size_t)ri * 65536 + (size_t)q * 32;
        aH[ri] = *(const f16x8*)p;
        aL[ri] = *(const f16x8*)(p + 16);
    }

    for (int kk = 0; kk < 32; ++kk) {
        WAIT_VM(0);                               // stage(kk) + A(kk) landed
        f16x8 bf0[8];
        #pragma unroll
        for (int t = 0; t < 8; ++t)
            bf0[t] = *(const f16x8*)&Yst[wave * 128 + t * 16 + ar][qs];
        WAIT_LGKM0();                             // frags in regs; stripe reusable
        if (kk < 31) {
            const int k1 = (kk + 1) * 32;
            #pragma unroll
            for (int t = 0; t < 8; ++t) {
                const int r = wave * 128 + t * 16 + lrow;
                async16(&yf[ybase + (size_t)r * 1024 + k1 + gcS],
                        &Yst[wave * 128 + t * 16][0]);
            }
        }
        #pragma unroll
        for (int ri = 0; ri < 4; ++ri)
            #pragma unroll
            for (int t = 0; t < 8; ++t) {
                s2[ri][t] = MFMA_F16(aH[ri], bf0[t], s2[ri][t]);
                s2[ri][t] = MFMA_F16(aL[ri], bf0[t], s2[ri][t]);
            }
        if (kk < 31) {
            #pragma unroll
            for (int ri = 0; ri < 4; ++ri) {
                const char* p = aptr + (size_t)ri * 65536
                              + (size_t)((kk + 1) * 4 + q) * 32;
                aH[ri] = *(const f16x8*)p;
                aL[ri] = *(const f16x8*)(p + 16);
            }
        }
    }

    // ---- phase 1: softmax, cross-wave combine via Red ----
    float pm[4][4];
    #pragma unroll
    for (int ri = 0; ri < 4; ++ri)
        #pragma unroll
        for (int r = 0; r < 4; ++r) {
            float m = -3.0e38f;
            #pragma unroll
            for (int t = 0; t < 8; ++t) m = fmaxf(m, s2[ri][t][r]);
            pm[ri][r] = m;
        }
    #pragma unroll
    for (int off = 1; off < 16; off <<= 1)
        #pragma unroll
        for (int ri = 0; ri < 4; ++ri)
            #pragma unroll
            for (int r = 0; r < 4; ++r)
                pm[ri][r] = fmaxf(pm[ri][r], __shfl_xor(pm[ri][r], off, 64));
    if (ar == 0) {
        #pragma unroll
        for (int ri = 0; ri < 4; ++ri)
            #pragma unroll
            for (int r = 0; r < 4; ++r)
                Red[wave * 64 + ri * 16 + q * 4 + r] = pm[ri][r];
    }
    __syncthreads();   // (1) maxes visible; all Yst reads complete
    float gm[4][4];
    #pragma unroll
    for (int ri = 0; ri < 4; ++ri)
        #pragma unroll
        for (int r = 0; r < 4; ++r) {
            const int row = ri * 16 + q * 4 + r;
            gm[ri][r] = fmaxf(fmaxf(Red[row], Red[64 + row]),
                              fmaxf(Red[128 + row], Red[192 + row]));
        }
    float ps[4][4];
    #pragma unroll
    for (int ri = 0; ri < 4; ++ri)
        #pragma unroll
        for (int r = 0; r < 4; ++r) {
            float sum = 0.f;
            #pragma unroll
            for (int t = 0; t < 8; ++t) {
                const float e = __expf(s2[ri][t][r] - gm[ri][r]);
                s2[ri][t][r] = e;
                sum += e;
            }
            ps[ri][r] = sum;
        }
    #pragma unroll
    for (int off = 1; off < 16; off <<= 1)
        #pragma unroll
        for (int ri = 0; ri < 4; ++ri)
            #pragma unroll
            for (int r = 0; r < 4; ++r)
                ps[ri][r] += __shfl_xor(ps[ri][r], off, 64);
    if (ar == 0) {
        #pragma unroll
        for (int ri = 0; ri < 4; ++ri)
            #pragma unroll
            for (int r = 0; r < 4; ++r)
                Red[256 + wave * 64 + ri * 16 + q * 4 + r] = ps[ri][r];
    }
    __syncthreads();   // (2) sums visible
    float inv[4][4];
    #pragma unroll
    for (int ri = 0; ri < 4; ++ri)
        #pragma unroll
        for (int r = 0; r < 4; ++r) {
            const int row = 256 + ri * 16 + q * 4 + r;
            inv[ri][r] = 1.0f / (Red[row] + Red[64 + row] + Red[128 + row] + Red[192 + row]);
        }
    #pragma unroll
    for (int ri = 0; ri < 4; ++ri)
        #pragma unroll
        for (int t = 0; t < 8; ++t)
            #pragma unroll
            for (int r = 0; r < 4; ++r)
                Pbuf[ri * 16 + q * 4 + r][wave * 128 + t * 16 + ar]
                    = (_Float16)(s2[ri][t][r] * inv[ri][r]);
    __syncthreads();   // (3) Pbuf complete before phase-2 reads

    // ---- phase 2: O = P @ y via yT; wave w -> d cols [dc*128+32w, +32) ----
    float* outF = (float*)outc;
    for (int dc = 0; dc < 8; ++dc) {
        f32x4 o2[4][2];
        #pragma unroll
        for (int ri = 0; ri < 4; ++ri)
            #pragma unroll
            for (int t = 0; t < 2; ++t)
                o2[ri][t] = (f32x4){0.f, 0.f, 0.f, 0.f};

        WAIT_LGKM0();   // prev-dc stripe reads done before overwrite
        #pragma unroll
        for (int t = 0; t < 2; ++t) {
            const int r = wave * 32 + t * 16 + lrow;
            async16(&yT[(size_t)(b * 1024 + dc * 128 + r) * 512 + gcS],
                    &Yt[wave * 32 + t * 16][0]);
        }
        for (int kk = 0; kk < 16; ++kk) {
            WAIT_VM(0);
            f16x8 a2[4], b2[2];
            #pragma unroll
            for (int ri = 0; ri < 4; ++ri)
                a2[ri] = *(const f16x8*)&Pbuf[ri * 16 + ar][kk * 32 + qk];
            #pragma unroll
            for (int t = 0; t < 2; ++t)
                b2[t] = *(const f16x8*)&Yt[wave * 32 + t * 16 + ar][qs];
            WAIT_LGKM0();
            if (kk < 15) {
                const int k1 = (kk + 1) * 32;
                #pragma unroll
                for (int t = 0; t < 2; ++t) {
                    const int r = wave * 32 + t * 16 + lrow;
                    async16(&yT[(size_t)(b * 1024 + dc * 128 + r) * 512 + k1 + gcS],
                            &Yt[wave * 32 + t * 16][0]);
                }
            }
            #pragma unroll
            for (int ri = 0; ri < 4; ++ri)
                #pragma unroll
                for (int t = 0; t < 2; ++t)
                    o2[ri][t] = MFMA_F16(a2[ri], b2[t], o2[ri][t]);
        }
        #pragma unroll
        for (int ri = 0; ri < 4; ++ri)
            #pragma unroll
            for (int t = 0; t < 2; ++t)
                #pragma unroll
                for (int r = 0; r < 4; ++r)
                    outF[(size_t)(pbase + ri * 16 + q * 4 + r) * 1024
                         + dc * 128 + wave * 32 + t * 16 + ar] = o2[ri][t][r];
    }
}

// ===================== fallback path (round-1, known good) ==================

__device__ __forceinline__ void cvt4(const float4 v, bf16x4& h, bf16x4& l) {
    const float f0 = v.x, f1 = v.y, f2 = v.z, f3 = v.w;
    const __bf16 h0 = (__bf16)f0, h1 = (__bf16)f1, h2 = (__bf16)f2, h3 = (__bf16)f3;
    h = (bf16x4){h0, h1, h2, h3};
    l = (bf16x4){(__bf16)(f0 - (float)h0), (__bf16)(f1 - (float)h1),
                 (__bf16)(f2 - (float)h2), (__bf16)(f3 - (float)h3)};
}

__global__ __launch_bounds__(256, 2)
void proj_kernel_fb(const float* __restrict__ x, const float* __restrict__ W,
                    const float* __restrict__ bias, float* __restrict__ proj)
{
    __shared__ __bf16 Ah[128][40];
    __shared__ __bf16 Al[128][40];
    __shared__ __bf16 Bh[128][40];
    __shared__ __bf16 Bl[128][40];

    const int tid = threadIdx.x, lane = tid & 63, wave = tid >> 6;
    const int wm = (wave >> 1) * 64, wn = (wave & 1) * 64;
    const int m0 = (blockIdx.x >> 3) * 128, n0 = (blockIdx.x & 7) * 128;
    const int ar = lane & 15, ak = (lane >> 4) * 8;

    f32x4 acc[4][4];
    #pragma unroll
    for (int i = 0; i < 4; ++i)
        #pragma unroll
        for (int j = 0; j < 4; ++j)
            acc[i][j] = (f32x4){0.f, 0.f, 0.f, 0.f};

    const int xr = tid >> 3, xc = (tid & 7) * 4;
    const int wkb = tid >> 5, wn4 = (tid & 31) * 4;

    for (int k0 = 0; k0 < 1024; k0 += 32) {
        __syncthreads();
        #pragma unroll
        for (int it = 0; it < 4; ++it) {
            const int r = xr + it * 32;
            const float4 v = *(const float4*)&x[(size_t)(m0 + r) * 1024 + k0 + xc];
            bf16x4 h, l; cvt4(v, h, l);
            *(bf16x4*)&Ah[r][xc] = h;
            *(bf16x4*)&Al[r][xc] = l;
        }
        {
            const size_t wb = (size_t)(k0 + wkb * 4) * 1024 + n0 + wn4;
            const float4 v0 = *(const float4*)&W[wb];
            const float4 v1 = *(const float4*)&W[wb + 1024];
            const float4 v2 = *(const float4*)&W[wb + 2048];
            const float4 v3 = *(const float4*)&W[wb + 3072];
            const float rv[4][4] = {{v0.x, v0.y, v0.z, v0.w},
                                    {v1.x, v1.y, v1.z, v1.w},
                                    {v2.x, v2.y, v2.z, v2.w},
                                    {v3.x, v3.y, v3.z, v3.w}};
            #pragma unroll
            for (int j = 0; j < 4; ++j) {
                bf16x4 h, l;
                #pragma unroll
                for (int kk = 0; kk < 4; ++kk) {
                    const float f = rv[kk][j];
                    const __bf16 hb = (__bf16)f;
                    h[kk] = hb;
                    l[kk] = (__bf16)(f - (float)hb);
                }
                *(bf16x4*)&Bh[wn4 + j][wkb * 4] = h;
                *(bf16x4*)&Bl[wn4 + j][wkb * 4] = l;
            }
        }
        __syncthreads();

        bf16x8 a_h[4], a_l[4], b_h[4], b_l[4];
        #pragma unroll
        for (int f = 0; f < 4; ++f) {
            a_h[f] = *(const bf16x8*)&Ah[wm + f * 16 + ar][ak];
            a_l[f] = *(const bf16x8*)&Al[wm + f * 16 + ar][ak];
            b_h[f] = *(const bf16x8*)&Bh[wn + f * 16 + ar][ak];
            b_l[f] = *(const bf16x8*)&Bl[wn + f * 16 + ar][ak];
        }
        #pragma unroll
        for (int i = 0; i < 4; ++i)
            #pragma unroll
            for (int j = 0; j < 4; ++j) {
                acc[i][j] = MFMA_BF16(a_h[i], b_h[j], acc[i][j]);
                acc[i][j] = MFMA_BF16(a_l[i], b_h[j], acc[i][j]);
                acc[i][j] = MFMA_BF16(a_h[i], b_l[j], acc[i][j]);
            }
    }

    const int q4 = (lane >> 4) * 4;
    #pragma unroll
    for (int j = 0; j < 4; ++j) {
        const int n = n0 + wn + j * 16 + ar;
        const float bv = bias[n];
        #pragma unroll
        for (int i = 0; i < 4; ++i) {
            const size_t base = (size_t)(m0 + wm + i * 16 + q4) * 1024 + n;
            #pragma unroll
            for (int r = 0; r < 4; ++r)
                proj[base + (size_t)r * 1024] = acc[i][j][r] + bv;
        }
    }
}

__global__ __launch_bounds__(256, 1)
void attn_kernel_fb(const float* __restrict__ y, float* __restrict__ out)
{
    __shared__ __bf16 Ph[64][40];
    __shared__ __bf16 Pl[64][40];
    __shared__ __bf16 Yh[128][40];
    __shared__ __bf16 Yl[128][40];
    __shared__ __bf16 Pbuf[64][520];

    const int tid = threadIdx.x, lane = tid & 63, wave = tid >> 6;
    const int b = blockIdx.x >> 3, sx0 = (blockIdx.x & 7) * 64;
    const size_t ybase = (size_t)b * 512 * 1024;
    const size_t pbase = ((size_t)b * 512 + sx0) * 1024;
    const int ar = lane & 15, ak = (lane >> 4) * 8, q = lane >> 4;

    f32x4 s[4][8];
    #pragma unroll
    for (int nb = 0; nb < 4; ++nb)
        #pragma unroll
        for (int f = 0; f < 8; ++f)
            s[nb][f] = (f32x4){0.f, 0.f, 0.f, 0.f};

    const int pr = tid >> 3, pc = (tid & 7) * 4;

    for (int k0 = 0; k0 < 1024; k0 += 32) {
        __syncthreads();
        #pragma unroll
        for (int it = 0; it < 2; ++it) {
            const int r = pr + it * 32;
            const float4 v = *(const float4*)&out[pbase + (size_t)r * 1024 + k0 + pc];
            bf16x4 h, l; cvt4(v, h, l);
            *(bf16x4*)&Ph[r][pc] = h;
            *(bf16x4*)&Pl[r][pc] = l;
        }
        #pragma unroll
        for (int nb = 0; nb < 4; ++nb) {
            if (nb) __syncthreads();
            const int sy0 = nb * 128;
            #pragma unroll
            for (int it = 0; it < 4; ++it) {
                const int r = pr + it * 32;
                const float4 v = *(const float4*)&y[ybase + (size_t)(sy0 + r) * 1024 + k0 + pc];
                bf16x4 h, l; cvt4(v, h, l);
                *(bf16x4*)&Yh[r][pc] = h;
                *(bf16x4*)&Yl[r][pc] = l;
            }
            __syncthreads();
            const bf16x8 a_h = *(const bf16x8*)&Ph[wave * 16 + ar][ak];
            const bf16x8 a_l = *(const bf16x8*)&Pl[wave * 16 + ar][ak];
            #pragma unroll
            for (int f = 0; f < 8; ++f) {
                const bf16x8 b_h = *(const bf16x8*)&Yh[f * 16 + ar][ak];
                const bf16x8 b_l = *(const bf16x8*)&Yl[f * 16 + ar][ak];
                s[nb][f] = MFMA_BF16(a_h, b_h, s[nb][f]);
                s[nb][f] = MFMA_BF16(a_l, b_h, s[nb][f]);
                s[nb][f] = MFMA_BF16(a_h, b_l, s[nb][f]);
            }
        }
    }

    #pragma unroll
    for (int r = 0; r < 4; ++r) {
        float m = -3.0e38f;
        #pragma unroll
        for (int nb = 0; nb < 4; ++nb)
            #pragma unroll
            for (int f = 0; f < 8; ++f)
                m = fmaxf(m, s[nb][f][r]);
        #pragma unroll
        for (int off = 1; off < 16; off <<= 1)
            m = fmaxf(m, __shfl_xor(m, off, 64));
        float sum = 0.f;
        #pragma unroll
        for (int nb = 0; nb < 4; ++nb)
            #pragma unroll
            for (int f = 0; f < 8; ++f) {
                const float e = __expf(s[nb][f][r] - m);
                s[nb][f][r] = e;
                sum += e;
            }
        #pragma unroll
        for (int off = 1; off < 16; off <<= 1)
            sum += __shfl_xor(sum, off, 64);
        const float inv = 1.0f / sum;
        #pragma unroll
        for (int nb = 0; nb < 4; ++nb)
            #pragma unroll
            for (int f = 0; f < 8; ++f)
                s[nb][f][r] *= inv;
    }
    #pragma unroll
    for (int nb = 0; nb < 4; ++nb)
        #pragma unroll
        for (int f = 0; f < 8; ++f)
            #pragma unroll
            for (int r = 0; r < 4; ++r)
                Pbuf[wave * 16 + q * 4 + r][nb * 128 + f * 16 + ar] = (__bf16)s[nb][f][r];

    const int y2kb = tid >> 5, y2n4 = (tid & 31) * 4;
    for (int d0 = 0; d0 < 1024; d0 += 128) {
        f32x4 o[8];
        #pragma unroll
        for (int f = 0; f < 8; ++f) o[f] = (f32x4){0.f, 0.f, 0.f, 0.f};

        for (int k0 = 0; k0 < 512; k0 += 32) {
            __syncthreads();
            const size_t yb = ybase + (size_t)(k0 + y2kb * 4) * 1024 + d0 + y2n4;
            const float4 v0 = *(const float4*)&y[yb];
            const float4 v1 = *(const float4*)&y[yb + 1024];
            const float4 v2 = *(const float4*)&y[yb + 2048];
            const float4 v3 = *(const float4*)&y[yb + 3072];
            const float rv[4][4] = {{v0.x, v0.y, v0.z, v0.w},
                                    {v1.x, v1.y, v1.z, v1.w},
                                    {v2.x, v2.y, v2.z, v2.w},
                                    {v3.x, v3.y, v3.z, v3.w}};
            #pragma unroll
            for (int j = 0; j < 4; ++j) {
                const bf16x4 h = (bf16x4){(__bf16)rv[0][j], (__bf16)rv[1][j],
                                          (__bf16)rv[2][j], (__bf16)rv[3][j]};
                *(bf16x4*)&Yh[y2n4 + j][y2kb * 4] = h;
            }
            __syncthreads();
            const bf16x8 a = *(const bf16x8*)&Pbuf[wave * 16 + ar][k0 + ak];
            #pragma unroll
            for (int f = 0; f < 8; ++f) {
                const bf16x8 bb = *(const bf16x8*)&Yh[f * 16 + ar][ak];
                o[f] = MFMA_BF16(a, bb, o[f]);
            }
        }
        #pragma unroll
        for (int f = 0; f < 8; ++f)
            #pragma unroll
            for (int r = 0; r < 4; ++r)
                out[pbase + (size_t)(wave * 16 + q * 4 + r) * 1024 + d0 + f * 16 + ar] = o[f][r];
    }
}

// ============================== launch ======================================

extern "C" void kernel_launch(void* const* d_in, const int* in_sizes, int n_in,
                              void* d_out, int out_size, void* d_ws, size_t ws_size,
                              hipStream_t stream) {
    (void)in_sizes; (void)n_in; (void)out_size;
    const float* x    = (const float*)d_in[0];
    const float* y    = (const float*)d_in[1];
    const float* W    = (const float*)d_in[2];
    const float* bias = (const float*)d_in[3];

    if (ws_size >= 268435456ULL) {
        _Float16* yf = (_Float16*)d_ws;
        _Float16* yT = yf + 33554432;
        _Float16* xh = yT + 33554432;
        _Float16* xl = xh + 33554432;
        _Float16* WT = xl + 33554432;
        const bool pre = ws_size >= 268435456ULL + 2097152ULL;

        if (pre) {
            prep_all_kernel<true><<<dim3(10496), dim3(256), 0, stream>>>(
                y, yf, yT, x, (f16x4*)xh, (f16x4*)xl, W, WT);
            proj_f16_kernel<true><<<dim3(2048), dim3(256), 0, stream>>>(xh, xl, WT, W, bias,
                                                                        (char*)d_out);
        } else {
            prep_all_kernel<false><<<dim3(10240), dim3(256), 0, stream>>>(
                y, yf, yT, x, (f16x4*)xh, (f16x4*)xl, W, nullptr);
            proj_f16_kernel<false><<<dim3(2048), dim3(256), 0, stream>>>(xh, xl, nullptr, W,
                                                                         bias, (char*)d_out);
        }
        attn_f16_kernel<<<dim3(512), dim3(256), 0, stream>>>(yf, yT, (char*)d_out);
    } else {
        float* out = (float*)d_out;
        proj_kernel_fb<<<dim3(256 * 8), dim3(256), 0, stream>>>(x, W, bias, out);
        attn_kernel_fb<<<dim3(64 * 8), dim3(256), 0, stream>>>(y, out);
    }
}

// Round 13
// 671.638 us; speedup vs baseline: 1.1085x; 1.0103x over previous
//
#include <hip/hip_runtime.h>

// ESIM layer: out = softmax((x@W + b) @ y^T) @ y
// B=64, Sx=Sy=512, D=1024, fp32 in/out.
//
// Round-14: final clean A/B on attn phase 2.
//  * attn: phase 0 + softmax = R11 VERBATIM (211us proven). Phase 2 swapped
//    to R4's direct-global version: wave owns d cols [w*256,+256) in 2
//    epochs, b2[8] straight from L2/L3-resident yT, o2[4][8] reuses s2's
//    dead registers, ZERO waits/barriers in k-loop (removes 128x WAIT_VM(0)
//    with ~40cyc cover + 128x WAIT_LGKM0). LDS 76800 -> 68608 (no Yt).
//  * proj: R12 double-buffer counted-vmcnt (kept, +10us proven).
//  * prep: merged kernel (kept).

typedef float  f32x4  __attribute__((ext_vector_type(4)));
typedef _Float16 f16x8 __attribute__((ext_vector_type(8)));
typedef _Float16 f16x4 __attribute__((ext_vector_type(4)));
typedef __bf16 bf16x8 __attribute__((ext_vector_type(8)));
typedef __bf16 bf16x4 __attribute__((ext_vector_type(4)));

#define MFMA_F16(a, b, c)  __builtin_amdgcn_mfma_f32_16x16x32_f16((a), (b), (c), 0, 0, 0)
#define MFMA_BF16(a, b, c) __builtin_amdgcn_mfma_f32_16x16x32_bf16((a), (b), (c), 0, 0, 0)

#define WAIT_VM(N)  do { asm volatile("s_waitcnt vmcnt(" #N ")" ::: "memory"); \
                         __builtin_amdgcn_sched_barrier(0); } while (0)
#define WAIT_LGKM0() do { asm volatile("s_waitcnt lgkmcnt(0)" ::: "memory"); \
                          __builtin_amdgcn_sched_barrier(0); } while (0)

__device__ __forceinline__ void async16(const void* g, void* lds) {
    __builtin_amdgcn_global_load_lds(
        (const __attribute__((address_space(1))) unsigned int*)g,
        (__attribute__((address_space(3))) unsigned int*)lds, 16, 0, 0);
}

// ========================= merged prep kernel ===============================
template <bool DOW>
__global__ void prep_all_kernel(const float* __restrict__ y, _Float16* __restrict__ yf,
                                _Float16* __restrict__ yT, const float* __restrict__ x,
                                f16x4* __restrict__ xh, f16x4* __restrict__ xl,
                                const float* __restrict__ W, _Float16* __restrict__ WT)
{
    __shared__ _Float16 LT[64][72];
    const int tid = threadIdx.x;
    const int bid = blockIdx.x;

    if (bid < 8192) {
        const int b   = bid >> 7;
        const int rem = bid & 127;
        const int sy0 = (rem >> 4) * 64;
        const int d0  = (rem & 15) * 64;
        const int r0 = tid >> 4;
        const int c4 = (tid & 15) * 4;
        #pragma unroll
        for (int i = 0; i < 4; ++i) {
            const int r = r0 + i * 16;
            const float4 v = *(const float4*)&y[((size_t)b * 512 + sy0 + r) * 1024 + d0 + c4];
            const f16x4 hv = {(_Float16)v.x, (_Float16)v.y, (_Float16)v.z, (_Float16)v.w};
            *(f16x4*)&yf[((size_t)b * 512 + sy0 + r) * 1024 + d0 + c4] = hv;
            #pragma unroll
            for (int cc = 0; cc < 4; ++cc) {
                const int c = (cc + (tid & 3)) & 3;
                LT[c4 + c][r] = hv[c];
            }
        }
        __syncthreads();
        #pragma unroll
        for (int i = 0; i < 4; ++i) {
            const int dr = r0 + i * 16;
            const f16x4 v = *(const f16x4*)&LT[dr][(tid & 15) * 4];
            *(f16x4*)&yT[((size_t)b * 1024 + d0 + dr) * 512 + sy0 + (tid & 15) * 4] = v;
        }
    } else if (bid < 10240) {
        int i = (bid - 8192) * 256 + tid;
        const float4* in = (const float4*)x;
        for (; i < 8388608; i += 2048 * 256) {
            const float4 v = in[i];
            const _Float16 h0 = (_Float16)v.x, h1 = (_Float16)v.y,
                           h2 = (_Float16)v.z, h3 = (_Float16)v.w;
            xh[i] = (f16x4){h0, h1, h2, h3};
            xl[i] = (f16x4){(_Float16)(v.x - (float)h0), (_Float16)(v.y - (float)h1),
                            (_Float16)(v.z - (float)h2), (_Float16)(v.w - (float)h3)};
        }
    } else if constexpr (DOW) {
        const int rem = bid - 10240;
        const int k0 = (rem >> 4) * 64;
        const int n0 = (rem & 15) * 64;
        const int r0 = tid >> 4;
        const int c4 = (tid & 15) * 4;
        #pragma unroll
        for (int i = 0; i < 4; ++i) {
            const int r = r0 + i * 16;
            const float4 v = *(const float4*)&W[(size_t)(k0 + r) * 1024 + n0 + c4];
            const f16x4 hv = {(_Float16)v.x, (_Float16)v.y, (_Float16)v.z, (_Float16)v.w};
            #pragma unroll
            for (int cc = 0; cc < 4; ++cc) {
                const int c = (cc + (tid & 3)) & 3;
                LT[c4 + c][r] = hv[c];
            }
        }
        __syncthreads();
        #pragma unroll
        for (int i = 0; i < 4; ++i) {
            const int dr = r0 + i * 16;
            const f16x4 v = *(const f16x4*)&LT[dr][(tid & 15) * 4];
            *(f16x4*)&WT[(size_t)(n0 + dr) * 1024 + k0 + (tid & 15) * 4] = v;
        }
    }
}

// ===================== K1: proj = x@W + b (fp16 2-term) =====================
// 128x128 tile, BK=32, 4 waves. DOUBLE-buffer LDS (48KB -> 3 blocks/CU) +
// raw s_barrier + counted vmcnt (1 tile in flight; vmcnt(6)/(4) mid-loop).
template <bool PRE>
__global__ __launch_bounds__(256, 3)
void proj_f16_kernel(const _Float16* __restrict__ xh, const _Float16* __restrict__ xl,
                     const _Float16* __restrict__ WT, const float* __restrict__ W,
                     const float* __restrict__ bias, char* __restrict__ outc)
{
    __shared__ __align__(16) char psm[49152];   // 2 bufs x (Xh 8K | Xl 8K | Wf 8K)

    const int tid = threadIdx.x, lane = tid & 63, wave = tid >> 6;
    const int swz = (blockIdx.x & 7) * 256 + (blockIdx.x >> 3);
    const int m0 = (swz >> 3) * 128, n0 = (swz & 7) * 128;
    const int wm = (wave >> 1) * 64, wn = (wave & 1) * 64;
    const int ar = lane & 15;
    const int qs  = ((lane >> 4) ^ ((lane >> 1) & 3)) * 8;
    const int gcS = ((lane & 3) ^ ((lane >> 3) & 3)) * 8;
    const int lrow = lane >> 2;
    const int wkb = tid & 7;
    const int wn4 = (tid >> 3) * 4;

    f32x4 acc[4][4];
    #pragma unroll
    for (int i = 0; i < 4; ++i)
        #pragma unroll
        for (int j = 0; j < 4; ++j)
            acc[i][j] = (f32x4){0.f, 0.f, 0.f, 0.f};

    auto STAGE = [&](int t, int bi) {
        const int k0 = t * 32;
        _Float16 (*Xh)[32] = (_Float16(*)[32])(psm + bi * 24576);
        _Float16 (*Xl)[32] = (_Float16(*)[32])(psm + bi * 24576 + 8192);
        _Float16 (*Wf)[32] = (_Float16(*)[32])(psm + bi * 24576 + 16384);
        #pragma unroll
        for (int tt = 0; tt < 2; ++tt) {
            const int r = wave * 32 + tt * 16 + lrow;
            async16(&xh[(size_t)(m0 + r) * 1024 + k0 + gcS], &Xh[wave * 32 + tt * 16][0]);
            async16(&xl[(size_t)(m0 + r) * 1024 + k0 + gcS], &Xl[wave * 32 + tt * 16][0]);
            if constexpr (PRE)
                async16(&WT[(size_t)(n0 + r) * 1024 + k0 + gcS], &Wf[wave * 32 + tt * 16][0]);
        }
        if constexpr (!PRE) {
            const size_t wb = (size_t)(k0 + wkb * 4) * 1024 + n0 + wn4;
            const float4 v0 = *(const float4*)&W[wb];
            const float4 v1 = *(const float4*)&W[wb + 1024];
            const float4 v2 = *(const float4*)&W[wb + 2048];
            const float4 v3 = *(const float4*)&W[wb + 3072];
            const float rv[4][4] = {{v0.x, v0.y, v0.z, v0.w},
                                    {v1.x, v1.y, v1.z, v1.w},
                                    {v2.x, v2.y, v2.z, v2.w},
                                    {v3.x, v3.y, v3.z, v3.w}};
            #pragma unroll
            for (int j = 0; j < 4; ++j) {
                const int R = wn4 + j;
                const f16x4 hv = {(_Float16)rv[0][j], (_Float16)rv[1][j],
                                  (_Float16)rv[2][j], (_Float16)rv[3][j]};
                const int c = (wkb >> 1) ^ ((R >> 1) & 3);
                *(f16x4*)&Wf[R][c * 8 + (wkb & 1) * 4] = hv;
            }
        }
    };

    // prologue: 2 tiles in flight
    STAGE(0, 0);
    STAGE(1, 1);

    for (int t = 0; t < 32; ++t) {
        const int bi = t & 1;
        if (t < 31) { if constexpr (PRE) WAIT_VM(6); else WAIT_VM(4); }
        else        { WAIT_VM(0); }
        __builtin_amdgcn_s_barrier();   // rendezvous: everyone's tile-t landed

        _Float16 (*Xh)[32] = (_Float16(*)[32])(psm + bi * 24576);
        _Float16 (*Xl)[32] = (_Float16(*)[32])(psm + bi * 24576 + 8192);
        _Float16 (*Wf)[32] = (_Float16(*)[32])(psm + bi * 24576 + 16384);
        f16x8 ah[4], al[4], bfv[4];
        #pragma unroll
        for (int f = 0; f < 4; ++f) {
            ah[f]  = *(const f16x8*)&Xh[wm + f * 16 + ar][qs];
            al[f]  = *(const f16x8*)&Xl[wm + f * 16 + ar][qs];
            bfv[f] = *(const f16x8*)&Wf[wn + f * 16 + ar][qs];
        }
        #pragma unroll
        for (int i = 0; i < 4; ++i)
            #pragma unroll
            for (int j = 0; j < 4; ++j) {
                acc[i][j] = MFMA_F16(ah[i], bfv[j], acc[i][j]);
                acc[i][j] = MFMA_F16(al[i], bfv[j], acc[i][j]);
            }
        __builtin_amdgcn_s_barrier();   // all reads of buf bi done

        if (t < 30) {
            STAGE(t + 2, bi);           // refill the buffer just consumed
            if constexpr (!PRE)
                asm volatile("s_waitcnt lgkmcnt(0)" ::: "memory");
        }
    }

    // ---- epilogue: 2 half-passes (32KB each): acc -> LDS -> coalesced out
    _Float16* Ep = (_Float16*)psm;      // [64 rows][256 f16] = 512B/row
    const int q4 = (lane >> 4) * 4;
    #pragma unroll
    for (int pass = 0; pass < 2; ++pass) {
        __syncthreads();                // psm free (k-loop done / pass-0 copied)
        if ((wave >> 1) == pass) {      // waves with wm == pass*64
            #pragma unroll
            for (int j = 0; j < 4; ++j) {
                const int nloc = wn + j * 16 + ar;
                const float bv = bias[n0 + nloc];
                const int nidx = (nloc >> 3) * 16 + (nloc & 7);
                #pragma unroll
                for (int i = 0; i < 4; ++i)
                    #pragma unroll
                    for (int r = 0; r < 4; ++r) {
                        const int Rl = i * 16 + q4 + r;   // 0..63 within half
                        const float v = acc[i][j][r] + bv;
                        const _Float16 h = (_Float16)v;
                        Ep[Rl * 256 + nidx]     = h;
                        Ep[Rl * 256 + nidx + 8] = (_Float16)(v - (float)h);
                    }
            }
        }
        __syncthreads();
        #pragma unroll
        for (int c = 0; c < 8; ++c) {   // 64 rows x 512B = 32KB out
            const int lin = c * 4096 + tid * 16;
            const int row = lin >> 9;
            const int off = lin & 511;
            *(float4*)(outc + (size_t)(m0 + pass * 64 + row) * 4096 + n0 * 4 + off)
                = *(const float4*)(psm + lin);
        }
    }
}

// ================= K2: attention per (batch, 64 sx rows), fp16 ==============
// Phase 0 + softmax: R11 verbatim (211us proven). Phase 2: R4's direct-global
// version -- wave w owns d cols [w*256,+256) in 2 epochs, b2 straight from
// L2/L3-resident yT, zero waits/barriers in k-loop. LDS 68608B.
__global__ __launch_bounds__(256, 2)
void attn_f16_kernel(const _Float16* __restrict__ yf, const _Float16* __restrict__ yT,
                     char* __restrict__ outc)
{
    __shared__ __align__(16) char smem[68608];
    _Float16 (*Yst)[32]   = (_Float16(*)[32])smem;            // [512][32] phase 0
    _Float16 (*Pbuf)[520] = (_Float16(*)[520])smem;           // [64][520] ph 1/2 overlay
    float*    Red         = (float*)(smem + 66560);           // [512]

    const int tid = threadIdx.x, lane = tid & 63, wave = tid >> 6;
    const int swzb = (blockIdx.x & 7) * 64 + (blockIdx.x >> 3);
    const int b = swzb >> 3, sx0 = (swzb & 7) * 64;
    const int pbase = b * 512 + sx0;
    const int ar = lane & 15, q = lane >> 4, qk = q * 8;
    const int qs  = (q ^ ((lane >> 1) & 3)) * 8;              // swizzled frag col
    const int gcS = ((lane & 3) ^ ((lane >> 3) & 3)) * 8;     // swizzled stage col
    const int lrow = lane >> 2;
    const size_t ybase = (size_t)b * 512 * 1024;

    // ---- phase 0: S = proj @ y^T, wave w -> sy cols [128w, 128w+128) ----
    f32x4 s2[4][8];
    #pragma unroll
    for (int ri = 0; ri < 4; ++ri)
        #pragma unroll
        for (int t = 0; t < 8; ++t)
            s2[ri][t] = (f32x4){0.f, 0.f, 0.f, 0.f};

    const char* aptr = outc + (size_t)(pbase + ar) * 4096;    // + ri*65536

    // prologue: stage kk=0 into own stripe, load A(0)
    #pragma unroll
    for (int t = 0; t < 8; ++t) {
        const int r = wave * 128 + t * 16 + lrow;
        async16(&yf[ybase + (size_t)r * 1024 + gcS], &Yst[wave * 128 + t * 16][0]);
    }
    f16x8 aH[4], aL[4];
    #pragma unroll
    for (int ri = 0; ri < 4; ++ri) {
        const char* p = aptr + (size_t)ri * 65536 + (size_t)q * 32;
        aH[ri] = *(const f16x8*)p;
        aL[ri] = *(const f16x8*)(p + 16);
    }

    for (int kk = 0; kk < 32; ++kk) {
        WAIT_VM(0);                               // stage(kk) + A(kk) landed
        f16x8 bf0[8];
        #pragma unroll
        for (int t = 0; t < 8; ++t)
            bf0[t] = *(const f16x8*)&Yst[wave * 128 + t * 16 + ar][qs];
        WAIT_LGKM0();                             // frags in regs; stripe reusable
        if (kk < 31) {
            const int k1 = (kk + 1) * 32;
            #pragma unroll
            for (int t = 0; t < 8; ++t) {
                const int r = wave * 128 + t * 16 + lrow;
                async16(&yf[ybase + (size_t)r * 1024 + k1 + gcS],
                        &Yst[wave * 128 + t * 16][0]);
            }
        }
        #pragma unroll
        for (int ri = 0; ri < 4; ++ri)
            #pragma unroll
            for (int t = 0; t < 8; ++t) {
                s2[ri][t] = MFMA_F16(aH[ri], bf0[t], s2[ri][t]);
                s2[ri][t] = MFMA_F16(aL[ri], bf0[t], s2[ri][t]);
            }
        if (kk < 31) {
            #pragma unroll
            for (int ri = 0; ri < 4; ++ri) {
                const char* p = aptr + (size_t)ri * 65536
                              + (size_t)((kk + 1) * 4 + q) * 32;
                aH[ri] = *(const f16x8*)p;
                aL[ri] = *(const f16x8*)(p + 16);
            }
        }
    }

    // ---- phase 1: softmax, cross-wave combine via Red ----
    float pm[4][4];
    #pragma unroll
    for (int ri = 0; ri < 4; ++ri)
        #pragma unroll
        for (int r = 0; r < 4; ++r) {
            float m = -3.0e38f;
            #pragma unroll
            for (int t = 0; t < 8; ++t) m = fmaxf(m, s2[ri][t][r]);
            pm[ri][r] = m;
        }
    #pragma unroll
    for (int off = 1; off < 16; off <<= 1)
        #pragma unroll
        for (int ri = 0; ri < 4; ++ri)
            #pragma unroll
            for (int r = 0; r < 4; ++r)
                pm[ri][r] = fmaxf(pm[ri][r], __shfl_xor(pm[ri][r], off, 64));
    if (ar == 0) {
        #pragma unroll
        for (int ri = 0; ri < 4; ++ri)
            #pragma unroll
            for (int r = 0; r < 4; ++r)
                Red[wave * 64 + ri * 16 + q * 4 + r] = pm[ri][r];
    }
    __syncthreads();   // (1) maxes visible; all Yst reads complete
    float gm[4][4];
    #pragma unroll
    for (int ri = 0; ri < 4; ++ri)
        #pragma unroll
        for (int r = 0; r < 4; ++r) {
            const int row = ri * 16 + q * 4 + r;
            gm[ri][r] = fmaxf(fmaxf(Red[row], Red[64 + row]),
                              fmaxf(Red[128 + row], Red[192 + row]));
        }
    float ps[4][4];
    #pragma unroll
    for (int ri = 0; ri < 4; ++ri)
        #pragma unroll
        for (int r = 0; r < 4; ++r) {
            float sum = 0.f;
            #pragma unroll
            for (int t = 0; t < 8; ++t) {
                const float e = __expf(s2[ri][t][r] - gm[ri][r]);
                s2[ri][t][r] = e;
                sum += e;
            }
            ps[ri][r] = sum;
        }
    #pragma unroll
    for (int off = 1; off < 16; off <<= 1)
        #pragma unroll
        for (int ri = 0; ri < 4; ++ri)
            #pragma unroll
            for (int r = 0; r < 4; ++r)
                ps[ri][r] += __shfl_xor(ps[ri][r], off, 64);
    if (ar == 0) {
        #pragma unroll
        for (int ri = 0; ri < 4; ++ri)
            #pragma unroll
            for (int r = 0; r < 4; ++r)
                Red[256 + wave * 64 + ri * 16 + q * 4 + r] = ps[ri][r];
    }
    __syncthreads();   // (2) sums visible
    float inv[4][4];
    #pragma unroll
    for (int ri = 0; ri < 4; ++ri)
        #pragma unroll
        for (int r = 0; r < 4; ++r) {
            const int row = 256 + ri * 16 + q * 4 + r;
            inv[ri][r] = 1.0f / (Red[row] + Red[64 + row] + Red[128 + row] + Red[192 + row]);
        }
    #pragma unroll
    for (int ri = 0; ri < 4; ++ri)
        #pragma unroll
        for (int t = 0; t < 8; ++t)
            #pragma unroll
            for (int r = 0; r < 4; ++r)
                Pbuf[ri * 16 + q * 4 + r][wave * 128 + t * 16 + ar]
                    = (_Float16)(s2[ri][t][r] * inv[ri][r]);
    __syncthreads();   // (3) Pbuf complete before phase-2 reads

    // ---- phase 2: O = P @ y via yT; wave w -> d cols [w*256, +256), 2 epochs ----
    float* outF = (float*)outc;
    #pragma unroll
    for (int dc = 0; dc < 2; ++dc) {
        f32x4 o2[4][8];
        #pragma unroll
        for (int ri = 0; ri < 4; ++ri)
            #pragma unroll
            for (int t = 0; t < 8; ++t)
                o2[ri][t] = (f32x4){0.f, 0.f, 0.f, 0.f};

        const _Float16* ytw = yT + ((size_t)b * 1024 + wave * 256 + dc * 128 + ar) * 512;

        for (int kk = 0; kk < 16; ++kk) {
            f16x8 a2[4], b2[8];
            #pragma unroll
            for (int ri = 0; ri < 4; ++ri)
                a2[ri] = *(const f16x8*)&Pbuf[ri * 16 + ar][kk * 32 + qk];
            #pragma unroll
            for (int t = 0; t < 8; ++t)
                b2[t] = *(const f16x8*)&ytw[(size_t)t * 16 * 512 + kk * 32 + qk];
            #pragma unroll
            for (int ri = 0; ri < 4; ++ri)
                #pragma unroll
                for (int t = 0; t < 8; ++t)
                    o2[ri][t] = MFMA_F16(a2[ri], b2[t], o2[ri][t]);
        }
        #pragma unroll
        for (int ri = 0; ri < 4; ++ri)
            #pragma unroll
            for (int t = 0; t < 8; ++t)
                #pragma unroll
                for (int r = 0; r < 4; ++r)
                    outF[(size_t)(pbase + ri * 16 + q * 4 + r) * 1024
                         + wave * 256 + dc * 128 + t * 16 + ar] = o2[ri][t][r];
    }
}

// ===================== fallback path (round-1, known good) ==================

__device__ __forceinline__ void cvt4(const float4 v, bf16x4& h, bf16x4& l) {
    const float f0 = v.x, f1 = v.y, f2 = v.z, f3 = v.w;
    const __bf16 h0 = (__bf16)f0, h1 = (__bf16)f1, h2 = (__bf16)f2, h3 = (__bf16)f3;
    h = (bf16x4){h0, h1, h2, h3};
    l = (bf16x4){(__bf16)(f0 - (float)h0), (__bf16)(f1 - (float)h1),
                 (__bf16)(f2 - (float)h2), (__bf16)(f3 - (float)h3)};
}

__global__ __launch_bounds__(256, 2)
void proj_kernel_fb(const float* __restrict__ x, const float* __restrict__ W,
                    const float* __restrict__ bias, float* __restrict__ proj)
{
    __shared__ __bf16 Ah[128][40];
    __shared__ __bf16 Al[128][40];
    __shared__ __bf16 Bh[128][40];
    __shared__ __bf16 Bl[128][40];

    const int tid = threadIdx.x, lane = tid & 63, wave = tid >> 6;
    const int wm = (wave >> 1) * 64, wn = (wave & 1) * 64;
    const int m0 = (blockIdx.x >> 3) * 128, n0 = (blockIdx.x & 7) * 128;
    const int ar = lane & 15, ak = (lane >> 4) * 8;

    f32x4 acc[4][4];
    #pragma unroll
    for (int i = 0; i < 4; ++i)
        #pragma unroll
        for (int j = 0; j < 4; ++j)
            acc[i][j] = (f32x4){0.f, 0.f, 0.f, 0.f};

    const int xr = tid >> 3, xc = (tid & 7) * 4;
    const int wkb = tid >> 5, wn4 = (tid & 31) * 4;

    for (int k0 = 0; k0 < 1024; k0 += 32) {
        __syncthreads();
        #pragma unroll
        for (int it = 0; it < 4; ++it) {
            const int r = xr + it * 32;
            const float4 v = *(const float4*)&x[(size_t)(m0 + r) * 1024 + k0 + xc];
            bf16x4 h, l; cvt4(v, h, l);
            *(bf16x4*)&Ah[r][xc] = h;
            *(bf16x4*)&Al[r][xc] = l;
        }
        {
            const size_t wb = (size_t)(k0 + wkb * 4) * 1024 + n0 + wn4;
            const float4 v0 = *(const float4*)&W[wb];
            const float4 v1 = *(const float4*)&W[wb + 1024];
            const float4 v2 = *(const float4*)&W[wb + 2048];
            const float4 v3 = *(const float4*)&W[wb + 3072];
            const float rv[4][4] = {{v0.x, v0.y, v0.z, v0.w},
                                    {v1.x, v1.y, v1.z, v1.w},
                                    {v2.x, v2.y, v2.z, v2.w},
                                    {v3.x, v3.y, v3.z, v3.w}};
            #pragma unroll
            for (int j = 0; j < 4; ++j) {
                bf16x4 h, l;
                #pragma unroll
                for (int kk = 0; kk < 4; ++kk) {
                    const float f = rv[kk][j];
                    const __bf16 hb = (__bf16)f;
                    h[kk] = hb;
                    l[kk] = (__bf16)(f - (float)hb);
                }
                *(bf16x4*)&Bh[wn4 + j][wkb * 4] = h;
                *(bf16x4*)&Bl[wn4 + j][wkb * 4] = l;
            }
        }
        __syncthreads();

        bf16x8 a_h[4], a_l[4], b_h[4], b_l[4];
        #pragma unroll
        for (int f = 0; f < 4; ++f) {
            a_h[f] = *(const bf16x8*)&Ah[wm + f * 16 + ar][ak];
            a_l[f] = *(const bf16x8*)&Al[wm + f * 16 + ar][ak];
            b_h[f] = *(const bf16x8*)&Bh[wn + f * 16 + ar][ak];
            b_l[f] = *(const bf16x8*)&Bl[wn + f * 16 + ar][ak];
        }
        #pragma unroll
        for (int i = 0; i < 4; ++i)
            #pragma unroll
            for (int j = 0; j < 4; ++j) {
                acc[i][j] = MFMA_BF16(a_h[i], b_h[j], acc[i][j]);
                acc[i][j] = MFMA_BF16(a_l[i], b_h[j], acc[i][j]);
                acc[i][j] = MFMA_BF16(a_h[i], b_l[j], acc[i][j]);
            }
    }

    const int q4 = (lane >> 4) * 4;
    #pragma unroll
    for (int j = 0; j < 4; ++j) {
        const int n = n0 + wn + j * 16 + ar;
        const float bv = bias[n];
        #pragma unroll
        for (int i = 0; i < 4; ++i) {
            const size_t base = (size_t)(m0 + wm + i * 16 + q4) * 1024 + n;
            #pragma unroll
            for (int r = 0; r < 4; ++r)
                proj[base + (size_t)r * 1024] = acc[i][j][r] + bv;
        }
    }
}

__global__ __launch_bounds__(256, 1)
void attn_kernel_fb(const float* __restrict__ y, float* __restrict__ out)
{
    __shared__ __bf16 Ph[64][40];
    __shared__ __bf16 Pl[64][40];
    __shared__ __bf16 Yh[128][40];
    __shared__ __bf16 Yl[128][40];
    __shared__ __bf16 Pbuf[64][520];

    const int tid = threadIdx.x, lane = tid & 63, wave = tid >> 6;
    const int b = blockIdx.x >> 3, sx0 = (blockIdx.x & 7) * 64;
    const size_t ybase = (size_t)b * 512 * 1024;
    const size_t pbase = ((size_t)b * 512 + sx0) * 1024;
    const int ar = lane & 15, ak = (lane >> 4) * 8, q = lane >> 4;

    f32x4 s[4][8];
    #pragma unroll
    for (int nb = 0; nb < 4; ++nb)
        #pragma unroll
        for (int f = 0; f < 8; ++f)
            s[nb][f] = (f32x4){0.f, 0.f, 0.f, 0.f};

    const int pr = tid >> 3, pc = (tid & 7) * 4;

    for (int k0 = 0; k0 < 1024; k0 += 32) {
        __syncthreads();
        #pragma unroll
        for (int it = 0; it < 2; ++it) {
            const int r = pr + it * 32;
            const float4 v = *(const float4*)&out[pbase + (size_t)r * 1024 + k0 + pc];
            bf16x4 h, l; cvt4(v, h, l);
            *(bf16x4*)&Ph[r][pc] = h;
            *(bf16x4*)&Pl[r][pc] = l;
        }
        #pragma unroll
        for (int nb = 0; nb < 4; ++nb) {
            if (nb) __syncthreads();
            const int sy0 = nb * 128;
            #pragma unroll
            for (int it = 0; it < 4; ++it) {
                const int r = pr + it * 32;
                const float4 v = *(const float4*)&y[ybase + (size_t)(sy0 + r) * 1024 + k0 + pc];
                bf16x4 h, l; cvt4(v, h, l);
                *(bf16x4*)&Yh[r][pc] = h;
                *(bf16x4*)&Yl[r][pc] = l;
            }
            __syncthreads();
            const bf16x8 a_h = *(const bf16x8*)&Ph[wave * 16 + ar][ak];
            const bf16x8 a_l = *(const bf16x8*)&Pl[wave * 16 + ar][ak];
            #pragma unroll
            for (int f = 0; f < 8; ++f) {
                const bf16x8 b_h = *(const bf16x8*)&Yh[f * 16 + ar][ak];
                const bf16x8 b_l = *(const bf16x8*)&Yl[f * 16 + ar][ak];
                s[nb][f] = MFMA_BF16(a_h, b_h, s[nb][f]);
                s[nb][f] = MFMA_BF16(a_l, b_h, s[nb][f]);
                s[nb][f] = MFMA_BF16(a_h, b_l, s[nb][f]);
            }
        }
    }

    #pragma unroll
    for (int r = 0; r < 4; ++r) {
        float m = -3.0e38f;
        #pragma unroll
        for (int nb = 0; nb < 4; ++nb)
            #pragma unroll
            for (int f = 0; f < 8; ++f)
                m = fmaxf(m, s[nb][f][r]);
        #pragma unroll
        for (int off = 1; off < 16; off <<= 1)
            m = fmaxf(m, __shfl_xor(m, off, 64));
        float sum = 0.f;
        #pragma unroll
        for (int nb = 0; nb < 4; ++nb)
            #pragma unroll
            for (int f = 0; f < 8; ++f) {
                const float e = __expf(s[nb][f][r] - m);
                s[nb][f][r] = e;
                sum += e;
            }
        #pragma unroll
        for (int off = 1; off < 16; off <<= 1)
            sum += __shfl_xor(sum, off, 64);
        const float inv = 1.0f / sum;
        #pragma unroll
        for (int nb = 0; nb < 4; ++nb)
            #pragma unroll
            for (int f = 0; f < 8; ++f)
                s[nb][f][r] *= inv;
    }
    #pragma unroll
    for (int nb = 0; nb < 4; ++nb)
        #pragma unroll
        for (int f = 0; f < 8; ++f)
            #pragma unroll
            for (int r = 0; r < 4; ++r)
                Pbuf[wave * 16 + q * 4 + r][nb * 128 + f * 16 + ar] = (__bf16)s[nb][f][r];

    const int y2kb = tid >> 5, y2n4 = (tid & 31) * 4;
    for (int d0 = 0; d0 < 1024; d0 += 128) {
        f32x4 o[8];
        #pragma unroll
        for (int f = 0; f < 8; ++f) o[f] = (f32x4){0.f, 0.f, 0.f, 0.f};

        for (int k0 = 0; k0 < 512; k0 += 32) {
            __syncthreads();
            const size_t yb = ybase + (size_t)(k0 + y2kb * 4) * 1024 + d0 + y2n4;
            const float4 v0 = *(const float4*)&y[yb];
            const float4 v1 = *(const float4*)&y[yb + 1024];
            const float4 v2 = *(const float4*)&y[yb + 2048];
            const float4 v3 = *(const float4*)&y[yb + 3072];
            const float rv[4][4] = {{v0.x, v0.y, v0.z, v0.w},
                                    {v1.x, v1.y, v1.z, v1.w},
                                    {v2.x, v2.y, v2.z, v2.w},
                                    {v3.x, v3.y, v3.z, v3.w}};
            #pragma unroll
            for (int j = 0; j < 4; ++j) {
                const bf16x4 h = (bf16x4){(__bf16)rv[0][j], (__bf16)rv[1][j],
                                          (__bf16)rv[2][j], (__bf16)rv[3][j]};
                *(bf16x4*)&Yh[y2n4 + j][y2kb * 4] = h;
            }
            __syncthreads();
            const bf16x8 a = *(const bf16x8*)&Pbuf[wave * 16 + ar][k0 + ak];
            #pragma unroll
            for (int f = 0; f < 8; ++f) {
                const bf16x8 bb = *(const bf16x8*)&Yh[f * 16 + ar][ak];
                o[f] = MFMA_BF16(a, bb, o[f]);
            }
        }
        #pragma unroll
        for (int f = 0; f < 8; ++f)
            #pragma unroll
            for (int r = 0; r < 4; ++r)
                out[pbase + (size_t)(wave * 16 + q * 4 + r) * 1024 + d0 + f * 16 + ar] = o[f][r];
    }
}

// ============================== launch ======================================

extern "C" void kernel_launch(void* const* d_in, const int* in_sizes, int n_in,
                              void* d_out, int out_size, void* d_ws, size_t ws_size,
                              hipStream_t stream) {
    (void)in_sizes; (void)n_in; (void)out_size;
    const float* x    = (const float*)d_in[0];
    const float* y    = (const float*)d_in[1];
    const float* W    = (const float*)d_in[2];
    const float* bias = (const float*)d_in[3];

    if (ws_size >= 268435456ULL) {
        _Float16* yf = (_Float16*)d_ws;
        _Float16* yT = yf + 33554432;
        _Float16* xh = yT + 33554432;
        _Float16* xl = xh + 33554432;
        _Float16* WT = xl + 33554432;
        const bool pre = ws_size >= 268435456ULL + 2097152ULL;

        if (pre) {
            prep_all_kernel<true><<<dim3(10496), dim3(256), 0, stream>>>(
                y, yf, yT, x, (f16x4*)xh, (f16x4*)xl, W, WT);
            proj_f16_kernel<true><<<dim3(2048), dim3(256), 0, stream>>>(xh, xl, WT, W, bias,
                                                                        (char*)d_out);
        } else {
            prep_all_kernel<false><<<dim3(10240), dim3(256), 0, stream>>>(
                y, yf, yT, x, (f16x4*)xh, (f16x4*)xl, W, nullptr);
            proj_f16_kernel<false><<<dim3(2048), dim3(256), 0, stream>>>(xh, xl, nullptr, W,
                                                                         bias, (char*)d_out);
        }
        attn_f16_kernel<<<dim3(512), dim3(256), 0, stream>>>(yf, yT, (char*)d_out);
    } else {
        float* out = (float*)d_out;
        proj_kernel_fb<<<dim3(256 * 8), dim3(256), 0, stream>>>(x, W, bias, out);
        attn_kernel_fb<<<dim3(64 * 8), dim3(256), 0, stream>>>(y, out);
    }
}